// Round 1
// baseline (906.502 us; speedup 1.0000x reference)
//
#include <hip/hip_runtime.h>
#include <math.h>

// Problem constants
#define BB 32
#define NN 8
#define PP 6
#define DD 96
#define EE 128
#define HH 8
#define II 64
#define KK 32
#define LSEQ 768            // N*D
#define ROWS (BB * LSEQ)    // 24576 token rows
#define OUTN 128
#define KOUT (LSEQ * EE)    // 98304

// ---------------------------------------------------------------------------
// Embed: row-normalize x, cosine-argmax prototype per (row,d), project both
// through emb_w/proj_w, add positional encoding. One block per row.
// ---------------------------------------------------------------------------
__global__ __launch_bounds__(128) void embed_kernel(
    const float* __restrict__ x, const float* __restrict__ prot,
    const float* __restrict__ emb_w, const float* __restrict__ emb_b,
    const float* __restrict__ proj_w, const float* __restrict__ proj_b,
    float* __restrict__ seq)
{
    const int r = blockIdx.x;      // 0..24575  (= b*L + l)
    const int t = threadIdx.x;     // 0..127
    __shared__ float xrow[PP];
    __shared__ float sel[PP];

    if (t < PP) xrow[t] = x[r * PP + t];
    __syncthreads();

    float nx = 0.f;
    #pragma unroll
    for (int p = 0; p < PP; ++p) nx += xrow[p] * xrow[p];
    const float xinv = 1.f / fmaxf(sqrtf(nx), 1e-12f);

    const int d = r % DD;
    if (t < KK) {
        const float* pr = prot + (d * KK + t) * PP;
        float pp[PP];
        float np2 = 0.f;
        #pragma unroll
        for (int p = 0; p < PP; ++p) { pp[p] = pr[p]; np2 += pp[p] * pp[p]; }
        const float pinv = 1.f / fmaxf(sqrtf(np2), 1e-12f);
        float dot = 0.f;
        #pragma unroll
        for (int p = 0; p < PP; ++p) dot += xrow[p] * pp[p];
        float sim = dot * xinv * pinv;
        int k = t;
        // argmax over 32 lanes, first-index tie-break (matches jnp.argmax)
        #pragma unroll
        for (int off = 16; off; off >>= 1) {
            float osim = __shfl_down(sim, off);
            int   ok   = __shfl_down(k, off);
            if (osim > sim || (osim == sim && ok < k)) { sim = osim; k = ok; }
        }
        k = __shfl(k, 0);
        if (t == k) {
            #pragma unroll
            for (int p = 0; p < PP; ++p) sel[p] = pp[p] * pinv;
        }
    }
    __syncthreads();

    // per-thread output feature t
    float acc = emb_b[t] + proj_b[t];
    #pragma unroll
    for (int p = 0; p < PP; ++p) acc = fmaf(xrow[p], emb_w[t * PP + p], acc);  // raw x
    #pragma unroll
    for (int p = 0; p < PP; ++p) acc = fmaf(sel[p], proj_w[t * PP + p], acc);

    const int lpos = r % LSEQ;
    const float twoj = (float)((t >> 1) * 2);
    const float div = __expf(twoj * (-9.210340371976184f / 128.0f));  // -ln(10000)/128
    const float ang = (float)lpos * div;
    const float pe = (t & 1) ? cosf(ang) : sinf(ang);
    seq[(size_t)r * EE + t] = acc + pe;
}

// ---------------------------------------------------------------------------
// Generic fp32 GEMM: C[M,N] = A[M,K] @ W[N,K]^T + bias[N], optional ELU.
// BM=BN=64, BK=32, 256 threads, 4x4 micro-tile. All dims multiples of tiles.
// ---------------------------------------------------------------------------
#define BM 64
#define BN 64
#define BK 32
__global__ __launch_bounds__(256) void gemm_bias(
    const float* __restrict__ A, const float* __restrict__ W,
    const float* __restrict__ bias, float* __restrict__ C,
    int M, int N, int K, int act)
{
    __shared__ float As[BM][BK + 1];
    __shared__ float Bs[BN][BK + 1];
    const int tid = threadIdx.x;
    const int tx = tid & 15;
    const int ty = tid >> 4;
    const int m0 = blockIdx.y * BM;
    const int n0 = blockIdx.x * BN;
    float acc[4][4] = {};

    for (int kb = 0; kb < K; kb += BK) {
        #pragma unroll
        for (int i = 0; i < 8; ++i) {
            int idx = tid + i * 256;
            int rr = idx >> 5, cc = idx & 31;
            As[rr][cc] = A[(size_t)(m0 + rr) * K + kb + cc];
            Bs[rr][cc] = W[(size_t)(n0 + rr) * K + kb + cc];
        }
        __syncthreads();
        #pragma unroll
        for (int kk = 0; kk < BK; ++kk) {
            float a[4], bv[4];
            #pragma unroll
            for (int i = 0; i < 4; ++i) a[i] = As[ty * 4 + i][kk];
            #pragma unroll
            for (int j = 0; j < 4; ++j) bv[j] = Bs[tx * 4 + j][kk];
            #pragma unroll
            for (int i = 0; i < 4; ++i)
                #pragma unroll
                for (int j = 0; j < 4; ++j)
                    acc[i][j] = fmaf(a[i], bv[j], acc[i][j]);
        }
        __syncthreads();
    }

    #pragma unroll
    for (int i = 0; i < 4; ++i) {
        int m = m0 + ty * 4 + i;
        #pragma unroll
        for (int j = 0; j < 4; ++j) {
            int n = n0 + tx * 4 + j;
            float v = acc[i][j] + bias[n];
            if (act == 1) v = v > 0.f ? v : expm1f(v);
            C[(size_t)m * N + n] = v;
        }
    }
}

// ---------------------------------------------------------------------------
// Attention: one block per (b,h). 768 threads = one Q row each. K/V staged in
// LDS in chunks of 384 rows (48 KB). Max-free softmax (logits are small).
// ---------------------------------------------------------------------------
#define HD 16
#define KCH 384
__global__ __launch_bounds__(768) void attention_kernel(
    const float* __restrict__ qkv, float* __restrict__ ctx)
{
    __shared__ float Ks[KCH][HD];
    __shared__ float Vs[KCH][HD];
    const int bh = blockIdx.x;
    const int b = bh >> 3, h = bh & 7;
    const int t = threadIdx.x;  // Q row
    const float* base = qkv + (size_t)b * LSEQ * 384;

    float q[HD];
    #pragma unroll
    for (int i = 0; i < HD; ++i) q[i] = base[(size_t)t * 384 + h * HD + i] * 0.25f;

    float l = 0.f;
    float acc[HD] = {};

    for (int c0 = 0; c0 < LSEQ; c0 += KCH) {
        __syncthreads();
        for (int idx = t; idx < KCH * HD; idx += 768) {
            int rr = idx >> 4, cc = idx & 15;
            Ks[rr][cc] = base[(size_t)(c0 + rr) * 384 + EE + h * HD + cc];
            Vs[rr][cc] = base[(size_t)(c0 + rr) * 384 + 2 * EE + h * HD + cc];
        }
        __syncthreads();
        for (int j = 0; j < KCH; ++j) {
            float s = 0.f;
            #pragma unroll
            for (int i = 0; i < HD; ++i) s = fmaf(q[i], Ks[j][i], s);
            float p = __expf(s);
            l += p;
            #pragma unroll
            for (int i = 0; i < HD; ++i) acc[i] = fmaf(p, Vs[j][i], acc[i]);
        }
    }
    const float inv = 1.f / l;
    float* cp = ctx + ((size_t)(b * LSEQ + t)) * EE + h * HD;
    #pragma unroll
    for (int i = 0; i < HD; ++i) cp[i] = acc[i] * inv;
}

// ---------------------------------------------------------------------------
// seq = LayerNorm(seq + branch) * gamma + beta. One block (128 thr) per row.
// ---------------------------------------------------------------------------
__global__ __launch_bounds__(128) void ln_residual_kernel(
    float* __restrict__ seq, const float* __restrict__ branch,
    const float* __restrict__ gamma, const float* __restrict__ beta)
{
    const int r = blockIdx.x, t = threadIdx.x;
    __shared__ float red[2];
    const int wid = t >> 6, lane = t & 63;

    float v = seq[(size_t)r * EE + t] + branch[(size_t)r * EE + t];
    float s = v;
    #pragma unroll
    for (int off = 32; off; off >>= 1) s += __shfl_down(s, off);
    if (lane == 0) red[wid] = s;
    __syncthreads();
    const float mean = (red[0] + red[1]) * (1.f / 128.f);
    const float d = v - mean;
    float s2 = d * d;
    #pragma unroll
    for (int off = 32; off; off >>= 1) s2 += __shfl_down(s2, off);
    __syncthreads();
    if (lane == 0) red[wid] = s2;
    __syncthreads();
    const float var = (red[0] + red[1]) * (1.f / 128.f);
    seq[(size_t)r * EE + t] = d / sqrtf(var + 1e-5f) * gamma[t] + beta[t];
}

// ---------------------------------------------------------------------------
// Final projection: out[b,o] = sum_k seq_flat[b,k]*out_w[o,k] + out_b[o]
// Split-K with atomics; out pre-initialized with bias.
// ---------------------------------------------------------------------------
__global__ void out_init_kernel(const float* __restrict__ out_b, float* __restrict__ out)
{
    int i = blockIdx.x * 256 + threadIdx.x;
    if (i < BB * OUTN) out[i] = out_b[i & (OUTN - 1)];
}

#define KC 1024
__global__ __launch_bounds__(256) void out_gemm_kernel(
    const float* __restrict__ seq, const float* __restrict__ out_w,
    float* __restrict__ out)
{
    __shared__ float wch[KC];
    __shared__ float part[4];
    const int o = blockIdx.y;           // 0..127
    const int k0 = blockIdx.x * KC;     // 96 chunks
    const int t = threadIdx.x;
    const int wid = t >> 6, lane = t & 63;

    #pragma unroll
    for (int i = 0; i < 4; ++i)
        wch[t + i * 256] = out_w[(size_t)o * KOUT + k0 + t + i * 256];
    __syncthreads();

    for (int b = 0; b < BB; ++b) {
        const float* z = seq + (size_t)b * KOUT + k0;
        float p = 0.f;
        #pragma unroll
        for (int i = 0; i < 4; ++i) p = fmaf(wch[t + i * 256], z[t + i * 256], p);
        #pragma unroll
        for (int off = 32; off; off >>= 1) p += __shfl_down(p, off);
        if (lane == 0) part[wid] = p;
        __syncthreads();
        if (t == 0) atomicAdd(&out[b * OUTN + o], part[0] + part[1] + part[2] + part[3]);
        __syncthreads();
    }
}

// ---------------------------------------------------------------------------
extern "C" void kernel_launch(void* const* d_in, const int* in_sizes, int n_in,
                              void* d_out, int out_size, void* d_ws, size_t ws_size,
                              hipStream_t stream)
{
    const float* x          = (const float*)d_in[0];
    const float* prototypes = (const float*)d_in[1];
    const float* emb_w      = (const float*)d_in[2];
    const float* emb_b      = (const float*)d_in[3];
    const float* proj_w     = (const float*)d_in[4];
    const float* proj_b     = (const float*)d_in[5];
    const float* in_proj_w  = (const float*)d_in[6];
    const float* in_proj_b  = (const float*)d_in[7];
    const float* out_proj_w = (const float*)d_in[8];
    const float* out_proj_b = (const float*)d_in[9];
    const float* ln1_s      = (const float*)d_in[10];
    const float* ln1_b      = (const float*)d_in[11];
    const float* ffn_w1     = (const float*)d_in[12];
    const float* ffn_b1     = (const float*)d_in[13];
    const float* ffn_w2     = (const float*)d_in[14];
    const float* ffn_b2     = (const float*)d_in[15];
    const float* ln2_s      = (const float*)d_in[16];
    const float* ln2_b      = (const float*)d_in[17];
    const float* out_w      = (const float*)d_in[18];
    const float* out_b      = (const float*)d_in[19];
    float* out = (float*)d_out;
    float* ws  = (float*)d_ws;

    // workspace layout (floats); tmp/hbuf reuse the qkv region (qkv is dead
    // after attention_kernel consumes it)
    float* seq  = ws;                       // 3,145,728
    float* qkv  = ws + 3145728;             // 9,437,184
    float* tmp  = ws + 3145728;             // aliases qkv   [0 .. 3.1M)
    float* hbuf = ws + 3145728 + 3145728;   // aliases qkv   [3.1M .. 4.7M)
    float* ctx  = ws + 12582912;            // 3,145,728  (total 62.9 MB)

    embed_kernel<<<ROWS, 128, 0, stream>>>(x, prototypes, emb_w, emb_b,
                                           proj_w, proj_b, seq);

    for (int l = 0; l < 2; ++l) {
        // qkv = seq @ Wqkv^T + b      [24576,128] x [384,128]^T
        gemm_bias<<<dim3(384 / BN, ROWS / BM), 256, 0, stream>>>(
            seq, in_proj_w + (size_t)l * 3 * EE * EE, in_proj_b + l * 3 * EE,
            qkv, ROWS, 3 * EE, EE, 0);
        attention_kernel<<<BB * HH, LSEQ, 0, stream>>>(qkv, ctx);
        // attn_out = ctx @ Wout^T + b
        gemm_bias<<<dim3(EE / BN, ROWS / BM), 256, 0, stream>>>(
            ctx, out_proj_w + (size_t)l * EE * EE, out_proj_b + l * EE,
            tmp, ROWS, EE, EE, 0);
        ln_residual_kernel<<<ROWS, 128, 0, stream>>>(seq, tmp,
                                                     ln1_s + l * EE, ln1_b + l * EE);
        // h = elu(seq @ W1^T + b1)    [24576,128] x [64,128]^T
        gemm_bias<<<dim3(II / BN, ROWS / BM), 256, 0, stream>>>(
            seq, ffn_w1 + (size_t)l * II * EE, ffn_b1 + l * II,
            hbuf, ROWS, II, EE, 1);
        // ffn_out = h @ W2^T + b2     [24576,64] x [128,64]^T
        gemm_bias<<<dim3(EE / BN, ROWS / BM), 256, 0, stream>>>(
            hbuf, ffn_w2 + (size_t)l * EE * II, ffn_b2 + l * EE,
            tmp, ROWS, EE, II, 0);
        ln_residual_kernel<<<ROWS, 128, 0, stream>>>(seq, tmp,
                                                     ln2_s + l * EE, ln2_b + l * EE);
    }

    out_init_kernel<<<(BB * OUTN + 255) / 256, 256, 0, stream>>>(out_b, out);
    out_gemm_kernel<<<dim3(KOUT / KC, OUTN), 256, 0, stream>>>(seq, out_w, out);
}

// Round 2
// 836.448 us; speedup vs baseline: 1.0838x; 1.0838x over previous
//
#include <hip/hip_runtime.h>
#include <hip/hip_bf16.h>
#include <math.h>

typedef unsigned short ushort_t;

// Problem constants
#define BB 32
#define PP 6
#define DD 96
#define EE 128
#define HH 8
#define II 64
#define KK 32
#define LSEQ 768            // N*D
#define ROWS (BB * LSEQ)    // 24576 token rows
#define OUTN 128
#define KOUT (LSEQ * EE)    // 98304

using bf16x8 = __attribute__((ext_vector_type(8))) short;
using f32x4  = __attribute__((ext_vector_type(4))) float;

__device__ __forceinline__ ushort_t f2b(float f) {
    __hip_bfloat16 h = __float2bfloat16(f);
    return *reinterpret_cast<ushort_t*>(&h);
}
__device__ __forceinline__ float b2f(ushort_t u) {
    __hip_bfloat16 h = *reinterpret_cast<__hip_bfloat16*>(&u);
    return __bfloat162float(h);
}

// ---------------------------------------------------------------------------
// Cast fp32 -> bf16 (weights, once per call)
// ---------------------------------------------------------------------------
__global__ void cast_bf16_kernel(const float* __restrict__ src,
                                 ushort_t* __restrict__ dst, int n)
{
    int i = blockIdx.x * 256 + threadIdx.x;
    if (i < n) dst[i] = f2b(src[i]);
}

// ---------------------------------------------------------------------------
// Embed: row-normalize x, cosine-argmax prototype per (row,d), project both
// through emb_w/proj_w, add positional encoding. One block per row.
// Writes fp32 seq (residual stream) + bf16 mirror (GEMM A-operand).
// ---------------------------------------------------------------------------
__global__ __launch_bounds__(128) void embed_kernel(
    const float* __restrict__ x, const float* __restrict__ prot,
    const float* __restrict__ emb_w, const float* __restrict__ emb_b,
    const float* __restrict__ proj_w, const float* __restrict__ proj_b,
    float* __restrict__ seq, ushort_t* __restrict__ seq_bf)
{
    const int r = blockIdx.x;      // 0..24575  (= b*L + l)
    const int t = threadIdx.x;     // 0..127
    __shared__ float xrow[PP];
    __shared__ float sel[PP];

    if (t < PP) xrow[t] = x[r * PP + t];
    __syncthreads();

    float nx = 0.f;
    #pragma unroll
    for (int p = 0; p < PP; ++p) nx += xrow[p] * xrow[p];
    const float xinv = 1.f / fmaxf(sqrtf(nx), 1e-12f);

    const int d = r % DD;
    if (t < KK) {
        const float* pr = prot + (d * KK + t) * PP;
        float pp[PP];
        float np2 = 0.f;
        #pragma unroll
        for (int p = 0; p < PP; ++p) { pp[p] = pr[p]; np2 += pp[p] * pp[p]; }
        const float pinv = 1.f / fmaxf(sqrtf(np2), 1e-12f);
        float dot = 0.f;
        #pragma unroll
        for (int p = 0; p < PP; ++p) dot += xrow[p] * pp[p];
        float sim = dot * xinv * pinv;
        int k = t;
        #pragma unroll
        for (int off = 16; off; off >>= 1) {
            float osim = __shfl_down(sim, off);
            int   ok   = __shfl_down(k, off);
            if (osim > sim || (osim == sim && ok < k)) { sim = osim; k = ok; }
        }
        k = __shfl(k, 0);
        if (t == k) {
            #pragma unroll
            for (int p = 0; p < PP; ++p) sel[p] = pp[p] * pinv;
        }
    }
    __syncthreads();

    float acc = emb_b[t] + proj_b[t];
    #pragma unroll
    for (int p = 0; p < PP; ++p) acc = fmaf(xrow[p], emb_w[t * PP + p], acc);
    #pragma unroll
    for (int p = 0; p < PP; ++p) acc = fmaf(sel[p], proj_w[t * PP + p], acc);

    const int lpos = r % LSEQ;
    const float twoj = (float)((t >> 1) * 2);
    const float div = __expf(twoj * (-9.210340371976184f / 128.0f));
    const float ang = (float)lpos * div;
    const float pe = (t & 1) ? cosf(ang) : sinf(ang);
    const float v = acc + pe;
    seq[(size_t)r * EE + t] = v;
    seq_bf[(size_t)r * EE + t] = f2b(v);
}

// ---------------------------------------------------------------------------
// MFMA bf16 GEMM: C[M,N] = A[M,K](bf16) @ W[N,K](bf16)^T + bias(f32)
// Block tile 128(M) x 64(N), 256 thr = 4 waves (each wave 32M x 64N).
// mfma_f32_16x16x32_bf16 lane maps (HW-verified, guide §3):
//   A frag: A[m=lane&15][k=(lane>>4)*8+j]   (8 contiguous k -> 16B)
//   B frag: B[k][n]=W[n][k]: n=lane&15, k=(lane>>4)*8+j
//   C/D:    col=lane&15, row=(lane>>4)*4+reg
// flags: 1 = ELU activation; 2 = output bf16 (else fp32)
// ---------------------------------------------------------------------------
__global__ __launch_bounds__(256) void gemm_mfma(
    const ushort_t* __restrict__ A, const ushort_t* __restrict__ W,
    const float* __restrict__ bias, void* __restrict__ Cout,
    int M, int N, int K, int flags)
{
    __shared__ ushort_t As[128 * 136];   // row stride kp = K+8 (pad: 16B, 2-way-free banks)
    __shared__ ushort_t Ws[64 * 136];
    const int t = threadIdx.x;
    const int wave = t >> 6, lane = t & 63;
    const int quad = lane >> 4, l16 = lane & 15;
    const int m0 = blockIdx.y * 128, n0 = blockIdx.x * 64;
    const int kp = K + 8;
    const int ak8 = K >> 3;  // 16B chunks per row

    for (int c = t; c < 128 * ak8; c += 256) {
        int row = c / ak8, col = c - row * ak8;
        *(bf16x8*)&As[row * kp + col * 8] =
            *(const bf16x8*)&A[(size_t)(m0 + row) * K + col * 8];
    }
    for (int c = t; c < 64 * ak8; c += 256) {
        int row = c / ak8, col = c - row * ak8;
        *(bf16x8*)&Ws[row * kp + col * 8] =
            *(const bf16x8*)&W[(size_t)(n0 + row) * K + col * 8];
    }
    __syncthreads();

    f32x4 acc[2][4];
    #pragma unroll
    for (int mt = 0; mt < 2; ++mt)
        #pragma unroll
        for (int nt = 0; nt < 4; ++nt)
            acc[mt][nt] = (f32x4){0.f, 0.f, 0.f, 0.f};

    const ushort_t* arow0 = &As[(wave * 32 + l16) * kp + quad * 8];
    const ushort_t* arow1 = arow0 + 16 * kp;
    const ushort_t* wrow  = &Ws[l16 * kp + quad * 8];

    for (int k0 = 0; k0 < K; k0 += 32) {
        bf16x8 a0 = *(const bf16x8*)(arow0 + k0);
        bf16x8 a1 = *(const bf16x8*)(arow1 + k0);
        #pragma unroll
        for (int nt = 0; nt < 4; ++nt) {
            bf16x8 b = *(const bf16x8*)(wrow + nt * 16 * kp + k0);
            acc[0][nt] = __builtin_amdgcn_mfma_f32_16x16x32_bf16(a0, b, acc[0][nt], 0, 0, 0);
            acc[1][nt] = __builtin_amdgcn_mfma_f32_16x16x32_bf16(a1, b, acc[1][nt], 0, 0, 0);
        }
    }

    #pragma unroll
    for (int mt = 0; mt < 2; ++mt) {
        #pragma unroll
        for (int nt = 0; nt < 4; ++nt) {
            const int n = n0 + nt * 16 + l16;
            const float bs = bias[n];
            #pragma unroll
            for (int r = 0; r < 4; ++r) {
                const int m = m0 + wave * 32 + mt * 16 + quad * 4 + r;
                float v = acc[mt][nt][r] + bs;
                if (flags & 1) v = v > 0.f ? v : expm1f(v);
                if (flags & 2) ((ushort_t*)Cout)[(size_t)m * N + n] = f2b(v);
                else           ((float*)Cout)[(size_t)m * N + n] = v;
            }
        }
    }
}

// ---------------------------------------------------------------------------
// Attention: one block per (b,h). 768 threads = one Q row each. K/V (bf16 in)
// staged as fp32 in LDS in chunks of 384 rows. Max-free softmax (logits are
// provably tiny). Writes ctx as bf16 (A-operand of out-proj GEMM).
// ---------------------------------------------------------------------------
#define HD 16
#define KCH 384
__global__ __launch_bounds__(768) void attention_kernel(
    const ushort_t* __restrict__ qkv, ushort_t* __restrict__ ctx)
{
    __shared__ float Ks[KCH][HD];
    __shared__ float Vs[KCH][HD];
    const int bh = blockIdx.x;
    const int b = bh >> 3, h = bh & 7;
    const int t = threadIdx.x;  // Q row
    const ushort_t* base = qkv + (size_t)b * LSEQ * 384;

    float q[HD];
    #pragma unroll
    for (int i = 0; i < HD; ++i) q[i] = b2f(base[(size_t)t * 384 + h * HD + i]) * 0.25f;

    float l = 0.f;
    float acc[HD] = {};

    for (int c0 = 0; c0 < LSEQ; c0 += KCH) {
        __syncthreads();
        for (int idx = t; idx < KCH * HD; idx += 768) {
            int rr = idx >> 4, cc = idx & 15;
            Ks[rr][cc] = b2f(base[(size_t)(c0 + rr) * 384 + EE + h * HD + cc]);
            Vs[rr][cc] = b2f(base[(size_t)(c0 + rr) * 384 + 2 * EE + h * HD + cc]);
        }
        __syncthreads();
        for (int j = 0; j < KCH; ++j) {
            float s = 0.f;
            #pragma unroll
            for (int i = 0; i < HD; ++i) s = fmaf(q[i], Ks[j][i], s);
            float p = __expf(s);
            l += p;
            #pragma unroll
            for (int i = 0; i < HD; ++i) acc[i] = fmaf(p, Vs[j][i], acc[i]);
        }
    }
    const float inv = 1.f / l;
    ushort_t* cp = ctx + ((size_t)(b * LSEQ + t)) * EE + h * HD;
    #pragma unroll
    for (int i = 0; i < HD; ++i) cp[i] = f2b(acc[i] * inv);
}

// ---------------------------------------------------------------------------
// seq = LayerNorm(seq + branch) * gamma + beta. Writes fp32 + bf16 mirror.
// ---------------------------------------------------------------------------
__global__ __launch_bounds__(128) void ln_residual_kernel(
    float* __restrict__ seq, ushort_t* __restrict__ seq_bf,
    const float* __restrict__ branch,
    const float* __restrict__ gamma, const float* __restrict__ beta)
{
    const int r = blockIdx.x, t = threadIdx.x;
    __shared__ float red[2];
    const int wid = t >> 6, lane = t & 63;

    float v = seq[(size_t)r * EE + t] + branch[(size_t)r * EE + t];
    float s = v;
    #pragma unroll
    for (int off = 32; off; off >>= 1) s += __shfl_down(s, off);
    if (lane == 0) red[wid] = s;
    __syncthreads();
    const float mean = (red[0] + red[1]) * (1.f / 128.f);
    const float d = v - mean;
    float s2 = d * d;
    #pragma unroll
    for (int off = 32; off; off >>= 1) s2 += __shfl_down(s2, off);
    __syncthreads();
    if (lane == 0) red[wid] = s2;
    __syncthreads();
    const float var = (red[0] + red[1]) * (1.f / 128.f);
    const float y = d / sqrtf(var + 1e-5f) * gamma[t] + beta[t];
    seq[(size_t)r * EE + t] = y;
    seq_bf[(size_t)r * EE + t] = f2b(y);
}

// ---------------------------------------------------------------------------
// Final projection out[b,o] = seq_flat[b,:]·out_w[o,:] + out_b[o].
// Grid = 512 k-chunks of 192. Per block: stage seq[32][192] in LDS; wave w
// owns k-sub [w*48,w*48+48), half-wave owns 24; lane covers 4 o's x all 32 b
// in registers (seq4 LDS reads broadcast across lanes). LDS-atomic reduce
// across the 8 (wave,half) groups, then global atomicAdd (out pre-init=bias).
// ---------------------------------------------------------------------------
#define OKC 192
#define SQS 196   // padded row stride (floats)
__global__ void out_init_kernel(const float* __restrict__ out_b, float* __restrict__ out)
{
    int i = blockIdx.x * 256 + threadIdx.x;
    if (i < BB * OUTN) out[i] = out_b[i & (OUTN - 1)];
}

__global__ __launch_bounds__(256) void out_gemm2(
    const float* __restrict__ seq, const float* __restrict__ out_w,
    float* __restrict__ out)
{
    __shared__ float sq[32 * SQS];      // 25,088 B
    __shared__ float accs[128 * 33];    // 16,896 B
    const int t = threadIdx.x;
    const int wave = t >> 6, lane = t & 63;
    const int half = lane >> 5, l32 = lane & 31;
    const int k0 = blockIdx.x * OKC;

    for (int c = t; c < 32 * 48; c += 256) {       // 48 float4 per row
        int row = c / 48, col = (c - row * 48) * 4;
        *(float4*)&sq[row * SQS + col] = *(const float4*)&seq[(size_t)row * KOUT + k0 + col];
    }
    for (int c = t; c < 128 * 33; c += 256) accs[c] = 0.f;
    __syncthreads();

    const int ls = wave * 48 + half * 24;          // LDS k base
    const size_t gs = (size_t)k0 + ls;             // global k base

    float acc[4][32];
    #pragma unroll
    for (int j = 0; j < 4; ++j)
        #pragma unroll
        for (int b = 0; b < 32; ++b) acc[j][b] = 0.f;

    for (int kk = 0; kk < 24; kk += 4) {
        float4 w4[4];
        #pragma unroll
        for (int j = 0; j < 4; ++j)
            w4[j] = *(const float4*)&out_w[(size_t)(l32 + j * 32) * KOUT + gs + kk];
        #pragma unroll
        for (int b = 0; b < 32; ++b) {
            float4 s4 = *(const float4*)&sq[b * SQS + ls + kk];
            #pragma unroll
            for (int j = 0; j < 4; ++j) {
                acc[j][b] = fmaf(w4[j].x, s4.x, acc[j][b]);
                acc[j][b] = fmaf(w4[j].y, s4.y, acc[j][b]);
                acc[j][b] = fmaf(w4[j].z, s4.z, acc[j][b]);
                acc[j][b] = fmaf(w4[j].w, s4.w, acc[j][b]);
            }
        }
    }

    // reduce 8 (wave,half) partials via LDS atomics
    #pragma unroll
    for (int j = 0; j < 4; ++j) {
        const int o = l32 + j * 32;
        #pragma unroll
        for (int b = 0; b < 32; ++b)
            atomicAdd(&accs[o * 33 + b], acc[j][b]);
    }
    __syncthreads();

    for (int c = t; c < BB * OUTN; c += 256) {
        int o = c >> 5, b = c & 31;
        atomicAdd(&out[b * OUTN + o], accs[o * 33 + b]);
    }
}

// ---------------------------------------------------------------------------
extern "C" void kernel_launch(void* const* d_in, const int* in_sizes, int n_in,
                              void* d_out, int out_size, void* d_ws, size_t ws_size,
                              hipStream_t stream)
{
    const float* x          = (const float*)d_in[0];
    const float* prototypes = (const float*)d_in[1];
    const float* emb_w      = (const float*)d_in[2];
    const float* emb_b      = (const float*)d_in[3];
    const float* proj_w     = (const float*)d_in[4];
    const float* proj_b     = (const float*)d_in[5];
    const float* in_proj_w  = (const float*)d_in[6];
    const float* in_proj_b  = (const float*)d_in[7];
    const float* out_proj_w = (const float*)d_in[8];
    const float* out_proj_b = (const float*)d_in[9];
    const float* ln1_s      = (const float*)d_in[10];
    const float* ln1_b      = (const float*)d_in[11];
    const float* ffn_w1     = (const float*)d_in[12];
    const float* ffn_b1     = (const float*)d_in[13];
    const float* ffn_w2     = (const float*)d_in[14];
    const float* ffn_b2     = (const float*)d_in[15];
    const float* ln2_s      = (const float*)d_in[16];
    const float* ln2_b      = (const float*)d_in[17];
    const float* out_w      = (const float*)d_in[18];
    const float* out_b      = (const float*)d_in[19];
    float* out = (float*)d_out;
    char* base = (char*)d_ws;

    // workspace layout (bytes)
    float*    seq    = (float*)base;                        // 12,582,912
    float*    tmp    = (float*)(base + 12582912);           // 12,582,912
    ushort_t* seq_bf = (ushort_t*)(base + 25165824);        //  6,291,456
    ushort_t* qkv_bf = (ushort_t*)(base + 31457280);        // 18,874,368
    ushort_t* ctx_bf = (ushort_t*)(base + 50331648);        //  6,291,456
    ushort_t* h_bf   = (ushort_t*)(base + 56623104);        //  3,145,728
    ushort_t* w_bf   = (ushort_t*)(base + 59768832);        //    327,680  (ends ~60.1 MB)

    ushort_t* w_in  = w_bf;            // [2][384][128]
    ushort_t* w_out = w_bf + 98304;    // [2][128][128]
    ushort_t* w_f1  = w_bf + 131072;   // [2][64][128]
    ushort_t* w_f2  = w_bf + 147456;   // [2][128][64]

    cast_bf16_kernel<<<(98304 + 255) / 256, 256, 0, stream>>>(in_proj_w, w_in, 98304);
    cast_bf16_kernel<<<(32768 + 255) / 256, 256, 0, stream>>>(out_proj_w, w_out, 32768);
    cast_bf16_kernel<<<(16384 + 255) / 256, 256, 0, stream>>>(ffn_w1, w_f1, 16384);
    cast_bf16_kernel<<<(16384 + 255) / 256, 256, 0, stream>>>(ffn_w2, w_f2, 16384);

    embed_kernel<<<ROWS, 128, 0, stream>>>(x, prototypes, emb_w, emb_b,
                                           proj_w, proj_b, seq, seq_bf);

    for (int l = 0; l < 2; ++l) {
        // qkv = seq @ Wqkv^T + b   -> bf16 [24576, 384]
        gemm_mfma<<<dim3(6, 192), 256, 0, stream>>>(
            seq_bf, w_in + (size_t)l * 98304 / 2, in_proj_b + l * 384,
            qkv_bf, ROWS, 384, 128, 2);
        attention_kernel<<<BB * HH, LSEQ, 0, stream>>>(qkv_bf, ctx_bf);
        // attn_out = ctx @ Wout^T + b  -> fp32 tmp
        gemm_mfma<<<dim3(2, 192), 256, 0, stream>>>(
            ctx_bf, w_out + (size_t)l * 16384, out_proj_b + l * 128,
            tmp, ROWS, 128, 128, 0);
        ln_residual_kernel<<<ROWS, 128, 0, stream>>>(seq, seq_bf, tmp,
                                                     ln1_s + l * EE, ln1_b + l * EE);
        // h = elu(seq @ W1^T + b1) -> bf16 [24576, 64]
        gemm_mfma<<<dim3(1, 192), 256, 0, stream>>>(
            seq_bf, w_f1 + (size_t)l * 8192, ffn_b1 + l * II,
            h_bf, ROWS, 64, 128, 1 | 2);
        // ffn_out = h @ W2^T + b2  -> fp32 tmp
        gemm_mfma<<<dim3(2, 192), 256, 0, stream>>>(
            h_bf, w_f2 + (size_t)l * 8192, ffn_b2 + l * EE,
            tmp, ROWS, 128, 64, 0);
        ln_residual_kernel<<<ROWS, 128, 0, stream>>>(seq, seq_bf, tmp,
                                                     ln2_s + l * EE, ln2_b + l * EE);
    }

    out_init_kernel<<<(BB * OUTN + 255) / 256, 256, 0, stream>>>(out_b, out);
    out_gemm2<<<KOUT / OKC, 256, 0, stream>>>(seq, out_w, out);
}

// Round 3
// 658.678 us; speedup vs baseline: 1.3762x; 1.2699x over previous
//
#include <hip/hip_runtime.h>
#include <hip/hip_bf16.h>
#include <math.h>

typedef unsigned short ushort_t;

// Problem constants
#define BB 32
#define PP 6
#define DD 96
#define EE 128
#define HH 8
#define II 64
#define KK 32
#define LSEQ 768            // N*D
#define ROWS (BB * LSEQ)    // 24576 token rows
#define OUTN 128
#define KOUT (LSEQ * EE)    // 98304

using bf16x8 = __attribute__((ext_vector_type(8))) short;
using f32x4  = __attribute__((ext_vector_type(4))) float;

__device__ __forceinline__ ushort_t f2b(float f) {
    __hip_bfloat16 h = __float2bfloat16(f);
    return *reinterpret_cast<ushort_t*>(&h);
}
__device__ __forceinline__ float b2f(ushort_t u) {
    __hip_bfloat16 h = *reinterpret_cast<__hip_bfloat16*>(&u);
    return __bfloat162float(h);
}

// ---------------------------------------------------------------------------
// Cast fp32 -> bf16 (weights, once per call)
// ---------------------------------------------------------------------------
__global__ void cast_bf16_kernel(const float* __restrict__ src,
                                 ushort_t* __restrict__ dst, int n)
{
    int i = blockIdx.x * 256 + threadIdx.x;
    if (i < n) dst[i] = f2b(src[i]);
}

// ---------------------------------------------------------------------------
// Embed: row-normalize x, cosine-argmax prototype per (row,d), project both
// through emb_w/proj_w, add positional encoding. One block per row.
// Writes fp32 seq (residual stream) + bf16 mirror (GEMM A-operand).
// ---------------------------------------------------------------------------
__global__ __launch_bounds__(128) void embed_kernel(
    const float* __restrict__ x, const float* __restrict__ prot,
    const float* __restrict__ emb_w, const float* __restrict__ emb_b,
    const float* __restrict__ proj_w, const float* __restrict__ proj_b,
    float* __restrict__ seq, ushort_t* __restrict__ seq_bf)
{
    const int r = blockIdx.x;      // 0..24575  (= b*L + l)
    const int t = threadIdx.x;     // 0..127
    __shared__ float xrow[PP];
    __shared__ float sel[PP];

    if (t < PP) xrow[t] = x[r * PP + t];
    __syncthreads();

    float nx = 0.f;
    #pragma unroll
    for (int p = 0; p < PP; ++p) nx += xrow[p] * xrow[p];
    const float xinv = 1.f / fmaxf(sqrtf(nx), 1e-12f);

    const int d = r % DD;
    if (t < KK) {
        const float* pr = prot + (d * KK + t) * PP;
        float pp[PP];
        float np2 = 0.f;
        #pragma unroll
        for (int p = 0; p < PP; ++p) { pp[p] = pr[p]; np2 += pp[p] * pp[p]; }
        const float pinv = 1.f / fmaxf(sqrtf(np2), 1e-12f);
        float dot = 0.f;
        #pragma unroll
        for (int p = 0; p < PP; ++p) dot += xrow[p] * pp[p];
        float sim = dot * xinv * pinv;
        int k = t;
        #pragma unroll
        for (int off = 16; off; off >>= 1) {
            float osim = __shfl_down(sim, off);
            int   ok   = __shfl_down(k, off);
            if (osim > sim || (osim == sim && ok < k)) { sim = osim; k = ok; }
        }
        k = __shfl(k, 0);
        if (t == k) {
            #pragma unroll
            for (int p = 0; p < PP; ++p) sel[p] = pp[p] * pinv;
        }
    }
    __syncthreads();

    float acc = emb_b[t] + proj_b[t];
    #pragma unroll
    for (int p = 0; p < PP; ++p) acc = fmaf(xrow[p], emb_w[t * PP + p], acc);
    #pragma unroll
    for (int p = 0; p < PP; ++p) acc = fmaf(sel[p], proj_w[t * PP + p], acc);

    const int lpos = r % LSEQ;
    const float twoj = (float)((t >> 1) * 2);
    const float div = __expf(twoj * (-9.210340371976184f / 128.0f));
    const float ang = (float)lpos * div;
    const float pe = (t & 1) ? cosf(ang) : sinf(ang);
    const float v = acc + pe;
    seq[(size_t)r * EE + t] = v;
    seq_bf[(size_t)r * EE + t] = f2b(v);
}

// ---------------------------------------------------------------------------
// MFMA bf16 GEMM: C[M,N] = A[M,K](bf16) @ W[N,K](bf16)^T + bias(f32)
// Block tile 128(M) x 64(N), 256 thr = 4 waves (each wave 32M x 64N).
// mfma_f32_16x16x32_bf16 lane maps (HW-verified, guide §3):
//   A frag: A[m=lane&15][k=(lane>>4)*8+j]
//   B frag: W[n=lane&15][k=(lane>>4)*8+j]
//   C/D:    col(n)=lane&15, row(m)=(lane>>4)*4+reg
// flags: 1 = ELU activation; 2 = output bf16 (else fp32)
// ---------------------------------------------------------------------------
__global__ __launch_bounds__(256) void gemm_mfma(
    const ushort_t* __restrict__ A, const ushort_t* __restrict__ W,
    const float* __restrict__ bias, void* __restrict__ Cout,
    int M, int N, int K, int flags)
{
    __shared__ ushort_t As[128 * 136];   // row stride kp = K+8
    __shared__ ushort_t Ws[64 * 136];
    const int t = threadIdx.x;
    const int wave = t >> 6, lane = t & 63;
    const int quad = lane >> 4, l16 = lane & 15;
    const int m0 = blockIdx.y * 128, n0 = blockIdx.x * 64;
    const int kp = K + 8;
    const int ak8 = K >> 3;  // 16B chunks per row

    for (int c = t; c < 128 * ak8; c += 256) {
        int row = c / ak8, col = c - row * ak8;
        *(bf16x8*)&As[row * kp + col * 8] =
            *(const bf16x8*)&A[(size_t)(m0 + row) * K + col * 8];
    }
    for (int c = t; c < 64 * ak8; c += 256) {
        int row = c / ak8, col = c - row * ak8;
        *(bf16x8*)&Ws[row * kp + col * 8] =
            *(const bf16x8*)&W[(size_t)(n0 + row) * K + col * 8];
    }
    __syncthreads();

    f32x4 acc[2][4];
    #pragma unroll
    for (int mt = 0; mt < 2; ++mt)
        #pragma unroll
        for (int nt = 0; nt < 4; ++nt)
            acc[mt][nt] = (f32x4){0.f, 0.f, 0.f, 0.f};

    const ushort_t* arow0 = &As[(wave * 32 + l16) * kp + quad * 8];
    const ushort_t* arow1 = arow0 + 16 * kp;
    const ushort_t* wrow  = &Ws[l16 * kp + quad * 8];

    for (int k0 = 0; k0 < K; k0 += 32) {
        bf16x8 a0 = *(const bf16x8*)(arow0 + k0);
        bf16x8 a1 = *(const bf16x8*)(arow1 + k0);
        #pragma unroll
        for (int nt = 0; nt < 4; ++nt) {
            bf16x8 b = *(const bf16x8*)(wrow + nt * 16 * kp + k0);
            acc[0][nt] = __builtin_amdgcn_mfma_f32_16x16x32_bf16(a0, b, acc[0][nt], 0, 0, 0);
            acc[1][nt] = __builtin_amdgcn_mfma_f32_16x16x32_bf16(a1, b, acc[1][nt], 0, 0, 0);
        }
    }

    #pragma unroll
    for (int mt = 0; mt < 2; ++mt) {
        #pragma unroll
        for (int nt = 0; nt < 4; ++nt) {
            const int n = n0 + nt * 16 + l16;
            const float bs = bias[n];
            #pragma unroll
            for (int r = 0; r < 4; ++r) {
                const int m = m0 + wave * 32 + mt * 16 + quad * 4 + r;
                float v = acc[mt][nt][r] + bs;
                if (flags & 1) v = v > 0.f ? v : expm1f(v);
                if (flags & 2) ((ushort_t*)Cout)[(size_t)m * N + n] = f2b(v);
                else           ((float*)Cout)[(size_t)m * N + n] = v;
            }
        }
    }
}

// ---------------------------------------------------------------------------
// Attention: one block per (b,h). 768 threads = one Q row each. K/V (bf16 in)
// staged as fp32 in LDS in chunks of 384 rows. Max-free softmax (logits are
// provably tiny). Writes ctx as bf16 (A-operand of out-proj GEMM).
// ---------------------------------------------------------------------------
#define HD 16
#define KCH 384
__global__ __launch_bounds__(768) void attention_kernel(
    const ushort_t* __restrict__ qkv, ushort_t* __restrict__ ctx)
{
    __shared__ float Ks[KCH][HD];
    __shared__ float Vs[KCH][HD];
    const int bh = blockIdx.x;
    const int b = bh >> 3, h = bh & 7;
    const int t = threadIdx.x;  // Q row
    const ushort_t* base = qkv + (size_t)b * LSEQ * 384;

    float q[HD];
    #pragma unroll
    for (int i = 0; i < HD; ++i) q[i] = b2f(base[(size_t)t * 384 + h * HD + i]) * 0.25f;

    float l = 0.f;
    float acc[HD] = {};

    for (int c0 = 0; c0 < LSEQ; c0 += KCH) {
        __syncthreads();
        for (int idx = t; idx < KCH * HD; idx += 768) {
            int rr = idx >> 4, cc = idx & 15;
            Ks[rr][cc] = b2f(base[(size_t)(c0 + rr) * 384 + EE + h * HD + cc]);
            Vs[rr][cc] = b2f(base[(size_t)(c0 + rr) * 384 + 2 * EE + h * HD + cc]);
        }
        __syncthreads();
        for (int j = 0; j < KCH; ++j) {
            float s = 0.f;
            #pragma unroll
            for (int i = 0; i < HD; ++i) s = fmaf(q[i], Ks[j][i], s);
            float p = __expf(s);
            l += p;
            #pragma unroll
            for (int i = 0; i < HD; ++i) acc[i] = fmaf(p, Vs[j][i], acc[i]);
        }
    }
    const float inv = 1.f / l;
    ushort_t* cp = ctx + ((size_t)(b * LSEQ + t)) * EE + h * HD;
    #pragma unroll
    for (int i = 0; i < HD; ++i) cp[i] = f2b(acc[i] * inv);
}

// ---------------------------------------------------------------------------
// seq = LayerNorm(seq + branch) * gamma + beta. Writes fp32 + bf16 mirror.
// ---------------------------------------------------------------------------
__global__ __launch_bounds__(128) void ln_residual_kernel(
    float* __restrict__ seq, ushort_t* __restrict__ seq_bf,
    const float* __restrict__ branch,
    const float* __restrict__ gamma, const float* __restrict__ beta)
{
    const int r = blockIdx.x, t = threadIdx.x;
    __shared__ float red[2];
    const int wid = t >> 6, lane = t & 63;

    float v = seq[(size_t)r * EE + t] + branch[(size_t)r * EE + t];
    float s = v;
    #pragma unroll
    for (int off = 32; off; off >>= 1) s += __shfl_down(s, off);
    if (lane == 0) red[wid] = s;
    __syncthreads();
    const float mean = (red[0] + red[1]) * (1.f / 128.f);
    const float d = v - mean;
    float s2 = d * d;
    #pragma unroll
    for (int off = 32; off; off >>= 1) s2 += __shfl_down(s2, off);
    __syncthreads();
    if (lane == 0) red[wid] = s2;
    __syncthreads();
    const float var = (red[0] + red[1]) * (1.f / 128.f);
    const float y = d / sqrtf(var + 1e-5f) * gamma[t] + beta[t];
    seq[(size_t)r * EE + t] = y;
    seq_bf[(size_t)r * EE + t] = f2b(y);
}

// ---------------------------------------------------------------------------
// Final projection, split-K MFMA. out[b,o] = seq_flat[b,:]·out_w[o,:]+out_b[o]
// A = seq_bf viewed as [32, 98304] bf16 (rows contiguous). B = out_w fp32,
// converted to bf16 in-register (W read exactly once from HBM, no cast pass).
// Grid: 512 blocks, each owns K-chunk of 192 (6 MFMA k-steps). 4 waves split
// N=128 into 32-row strips; acc[2 mtile][2 ntile] f32x4. Partials (no
// atomics!) -> part[blk][32][128] fp32, folded by out_reduce.
// ---------------------------------------------------------------------------
#define PKC 192
#define PNBLK (KOUT / PKC)   // 512
__global__ __launch_bounds__(256) void out_gemm3(
    const ushort_t* __restrict__ seqbf, const float* __restrict__ out_w,
    float* __restrict__ part)
{
    const int t = threadIdx.x;
    const int wave = t >> 6, lane = t & 63;
    const int quad = lane >> 4, l16 = lane & 15;
    const size_t k0 = (size_t)blockIdx.x * PKC;
    const int n0 = wave * 32;

    f32x4 acc[2][2];
    #pragma unroll
    for (int mt = 0; mt < 2; ++mt)
        #pragma unroll
        for (int nt = 0; nt < 2; ++nt)
            acc[mt][nt] = (f32x4){0.f, 0.f, 0.f, 0.f};

    const ushort_t* a0p = seqbf + (size_t)l16 * KOUT + k0 + quad * 8;
    const ushort_t* a1p = a0p + (size_t)16 * KOUT;
    const float* w0p = out_w + (size_t)(n0 + l16) * KOUT + k0 + quad * 8;
    const float* w1p = w0p + (size_t)16 * KOUT;

    #pragma unroll
    for (int ks = 0; ks < PKC; ks += 32) {
        bf16x8 a0 = *(const bf16x8*)(a0p + ks);
        bf16x8 a1 = *(const bf16x8*)(a1p + ks);
        float4 wa0 = *(const float4*)(w0p + ks);
        float4 wa1 = *(const float4*)(w0p + ks + 4);
        float4 wb0 = *(const float4*)(w1p + ks);
        float4 wb1 = *(const float4*)(w1p + ks + 4);
        bf16x8 bf0, bf1;
        bf0[0] = (short)f2b(wa0.x); bf0[1] = (short)f2b(wa0.y);
        bf0[2] = (short)f2b(wa0.z); bf0[3] = (short)f2b(wa0.w);
        bf0[4] = (short)f2b(wa1.x); bf0[5] = (short)f2b(wa1.y);
        bf0[6] = (short)f2b(wa1.z); bf0[7] = (short)f2b(wa1.w);
        bf1[0] = (short)f2b(wb0.x); bf1[1] = (short)f2b(wb0.y);
        bf1[2] = (short)f2b(wb0.z); bf1[3] = (short)f2b(wb0.w);
        bf1[4] = (short)f2b(wb1.x); bf1[5] = (short)f2b(wb1.y);
        bf1[6] = (short)f2b(wb1.z); bf1[7] = (short)f2b(wb1.w);
        acc[0][0] = __builtin_amdgcn_mfma_f32_16x16x32_bf16(a0, bf0, acc[0][0], 0, 0, 0);
        acc[1][0] = __builtin_amdgcn_mfma_f32_16x16x32_bf16(a1, bf0, acc[1][0], 0, 0, 0);
        acc[0][1] = __builtin_amdgcn_mfma_f32_16x16x32_bf16(a0, bf1, acc[0][1], 0, 0, 0);
        acc[1][1] = __builtin_amdgcn_mfma_f32_16x16x32_bf16(a1, bf1, acc[1][1], 0, 0, 0);
    }

    // part[blk][m][n]: m(row)=mt*16+quad*4+r, n(col)=n0+nt*16+l16
    float* pb = part + (size_t)blockIdx.x * (32 * 128);
    #pragma unroll
    for (int mt = 0; mt < 2; ++mt)
        #pragma unroll
        for (int nt = 0; nt < 2; ++nt)
            #pragma unroll
            for (int r = 0; r < 4; ++r)
                pb[(mt * 16 + quad * 4 + r) * 128 + n0 + nt * 16 + l16] = acc[mt][nt][r];
}

// out[i=b*128+n] = out_b[n] + sum_blk part[blk][b][n]
__global__ __launch_bounds__(256) void out_reduce(
    const float* __restrict__ part, const float* __restrict__ out_b,
    float* __restrict__ out)
{
    const int i = blockIdx.x * 256 + threadIdx.x;   // 0..4095
    const float* p = part + i;
    float s0 = 0.f, s1 = 0.f, s2 = 0.f, s3 = 0.f;
    for (int blk = 0; blk < PNBLK; blk += 4) {
        s0 += p[(size_t)blk * 4096];
        s1 += p[(size_t)(blk + 1) * 4096];
        s2 += p[(size_t)(blk + 2) * 4096];
        s3 += p[(size_t)(blk + 3) * 4096];
    }
    out[i] = out_b[i & (OUTN - 1)] + ((s0 + s1) + (s2 + s3));
}

// ---------------------------------------------------------------------------
extern "C" void kernel_launch(void* const* d_in, const int* in_sizes, int n_in,
                              void* d_out, int out_size, void* d_ws, size_t ws_size,
                              hipStream_t stream)
{
    const float* x          = (const float*)d_in[0];
    const float* prototypes = (const float*)d_in[1];
    const float* emb_w      = (const float*)d_in[2];
    const float* emb_b      = (const float*)d_in[3];
    const float* proj_w     = (const float*)d_in[4];
    const float* proj_b     = (const float*)d_in[5];
    const float* in_proj_w  = (const float*)d_in[6];
    const float* in_proj_b  = (const float*)d_in[7];
    const float* out_proj_w = (const float*)d_in[8];
    const float* out_proj_b = (const float*)d_in[9];
    const float* ln1_s      = (const float*)d_in[10];
    const float* ln1_b      = (const float*)d_in[11];
    const float* ffn_w1     = (const float*)d_in[12];
    const float* ffn_b1     = (const float*)d_in[13];
    const float* ffn_w2     = (const float*)d_in[14];
    const float* ffn_b2     = (const float*)d_in[15];
    const float* ln2_s      = (const float*)d_in[16];
    const float* ln2_b      = (const float*)d_in[17];
    const float* out_w      = (const float*)d_in[18];
    const float* out_b      = (const float*)d_in[19];
    float* out = (float*)d_out;
    char* base = (char*)d_ws;

    // workspace layout (bytes)
    float*    seq    = (float*)base;                        // 12,582,912
    float*    tmp    = (float*)(base + 12582912);           // 12,582,912
    ushort_t* seq_bf = (ushort_t*)(base + 25165824);        //  6,291,456
    ushort_t* qkv_bf = (ushort_t*)(base + 31457280);        // 18,874,368
    ushort_t* ctx_bf = (ushort_t*)(base + 50331648);        //  6,291,456
    ushort_t* h_bf   = (ushort_t*)(base + 56623104);        //  3,145,728
    ushort_t* w_bf   = (ushort_t*)(base + 59768832);        //    655,360 B region
    // part aliases tmp (dead after the last ln_residual): 512*32*128*4 = 8 MB
    float*    part   = (float*)(base + 12582912);

    ushort_t* w_in  = w_bf;            // [2][384][128]
    ushort_t* w_out = w_bf + 98304;    // [2][128][128]
    ushort_t* w_f1  = w_bf + 131072;   // [2][64][128]
    ushort_t* w_f2  = w_bf + 147456;   // [2][128][64]

    cast_bf16_kernel<<<(98304 + 255) / 256, 256, 0, stream>>>(in_proj_w, w_in, 98304);
    cast_bf16_kernel<<<(32768 + 255) / 256, 256, 0, stream>>>(out_proj_w, w_out, 32768);
    cast_bf16_kernel<<<(16384 + 255) / 256, 256, 0, stream>>>(ffn_w1, w_f1, 16384);
    cast_bf16_kernel<<<(16384 + 255) / 256, 256, 0, stream>>>(ffn_w2, w_f2, 16384);

    embed_kernel<<<ROWS, 128, 0, stream>>>(x, prototypes, emb_w, emb_b,
                                           proj_w, proj_b, seq, seq_bf);

    for (int l = 0; l < 2; ++l) {
        // qkv = seq @ Wqkv^T + b   -> bf16 [24576, 384]
        gemm_mfma<<<dim3(6, 192), 256, 0, stream>>>(
            seq_bf, w_in + (size_t)l * 49152, in_proj_b + l * 384,
            qkv_bf, ROWS, 384, 128, 2);
        attention_kernel<<<BB * HH, LSEQ, 0, stream>>>(qkv_bf, ctx_bf);
        // attn_out = ctx @ Wout^T + b  -> fp32 tmp
        gemm_mfma<<<dim3(2, 192), 256, 0, stream>>>(
            ctx_bf, w_out + (size_t)l * 16384, out_proj_b + l * 128,
            tmp, ROWS, 128, 128, 0);
        ln_residual_kernel<<<ROWS, 128, 0, stream>>>(seq, seq_bf, tmp,
                                                     ln1_s + l * EE, ln1_b + l * EE);
        // h = elu(seq @ W1^T + b1) -> bf16 [24576, 64]
        gemm_mfma<<<dim3(1, 192), 256, 0, stream>>>(
            seq_bf, w_f1 + (size_t)l * 8192, ffn_b1 + l * II,
            h_bf, ROWS, 64, 128, 1 | 2);
        // ffn_out = h @ W2^T + b2  -> fp32 tmp
        gemm_mfma<<<dim3(2, 192), 256, 0, stream>>>(
            h_bf, w_f2 + (size_t)l * 8192, ffn_b2 + l * EE,
            tmp, ROWS, 128, 64, 0);
        ln_residual_kernel<<<ROWS, 128, 0, stream>>>(seq, seq_bf, tmp,
                                                     ln2_s + l * EE, ln2_b + l * EE);
    }

    out_gemm3<<<PNBLK, 256, 0, stream>>>(seq_bf, out_w, part);
    out_reduce<<<BB * OUTN / 256, 256, 0, stream>>>(part, out_b, out);
}

// Round 4
// 457.060 us; speedup vs baseline: 1.9833x; 1.4411x over previous
//
#include <hip/hip_runtime.h>
#include <hip/hip_bf16.h>
#include <math.h>

typedef unsigned short ushort_t;

// Problem constants
#define BB 32
#define PP 6
#define DD 96
#define EE 128
#define HH 8
#define II 64
#define KK 32
#define LSEQ 768            // N*D
#define ROWS (BB * LSEQ)    // 24576 token rows
#define OUTN 128
#define KOUT (LSEQ * EE)    // 98304

using bf16x8 = __attribute__((ext_vector_type(8))) short;
using f32x4  = __attribute__((ext_vector_type(4))) float;

__device__ __forceinline__ ushort_t f2b(float f) {
    __hip_bfloat16 h = __float2bfloat16(f);
    return *reinterpret_cast<ushort_t*>(&h);
}
__device__ __forceinline__ float b2f(ushort_t u) {
    __hip_bfloat16 h = *reinterpret_cast<__hip_bfloat16*>(&u);
    return __bfloat162float(h);
}

// ---------------------------------------------------------------------------
// Cast fp32 -> bf16 (weights, once per call)
// ---------------------------------------------------------------------------
__global__ void cast_bf16_kernel(const float* __restrict__ src,
                                 ushort_t* __restrict__ dst, int n)
{
    int i = blockIdx.x * 256 + threadIdx.x;
    if (i < n) dst[i] = f2b(src[i]);
}

// ---------------------------------------------------------------------------
// Embed: row-normalize x, cosine-argmax prototype per (row,d), project both
// through emb_w/proj_w, add positional encoding. One block per row.
// Writes fp32 seq (residual stream) + bf16 mirror (GEMM A-operand).
// ---------------------------------------------------------------------------
__global__ __launch_bounds__(128) void embed_kernel(
    const float* __restrict__ x, const float* __restrict__ prot,
    const float* __restrict__ emb_w, const float* __restrict__ emb_b,
    const float* __restrict__ proj_w, const float* __restrict__ proj_b,
    float* __restrict__ seq, ushort_t* __restrict__ seq_bf)
{
    const int r = blockIdx.x;      // 0..24575  (= b*L + l)
    const int t = threadIdx.x;     // 0..127
    __shared__ float xrow[PP];
    __shared__ float sel[PP];

    if (t < PP) xrow[t] = x[r * PP + t];
    __syncthreads();

    float nx = 0.f;
    #pragma unroll
    for (int p = 0; p < PP; ++p) nx += xrow[p] * xrow[p];
    const float xinv = 1.f / fmaxf(sqrtf(nx), 1e-12f);

    const int d = r % DD;
    if (t < KK) {
        const float* pr = prot + (d * KK + t) * PP;
        float pp[PP];
        float np2 = 0.f;
        #pragma unroll
        for (int p = 0; p < PP; ++p) { pp[p] = pr[p]; np2 += pp[p] * pp[p]; }
        const float pinv = 1.f / fmaxf(sqrtf(np2), 1e-12f);
        float dot = 0.f;
        #pragma unroll
        for (int p = 0; p < PP; ++p) dot += xrow[p] * pp[p];
        float sim = dot * xinv * pinv;
        int k = t;
        #pragma unroll
        for (int off = 16; off; off >>= 1) {
            float osim = __shfl_down(sim, off);
            int   ok   = __shfl_down(k, off);
            if (osim > sim || (osim == sim && ok < k)) { sim = osim; k = ok; }
        }
        k = __shfl(k, 0);
        if (t == k) {
            #pragma unroll
            for (int p = 0; p < PP; ++p) sel[p] = pp[p] * pinv;
        }
    }
    __syncthreads();

    float acc = emb_b[t] + proj_b[t];
    #pragma unroll
    for (int p = 0; p < PP; ++p) acc = fmaf(xrow[p], emb_w[t * PP + p], acc);
    #pragma unroll
    for (int p = 0; p < PP; ++p) acc = fmaf(sel[p], proj_w[t * PP + p], acc);

    const int lpos = r % LSEQ;
    const float twoj = (float)((t >> 1) * 2);
    const float div = __expf(twoj * (-9.210340371976184f / 128.0f));
    const float ang = (float)lpos * div;
    const float pe = (t & 1) ? cosf(ang) : sinf(ang);
    const float v = acc + pe;
    seq[(size_t)r * EE + t] = v;
    seq_bf[(size_t)r * EE + t] = f2b(v);
}

// ---------------------------------------------------------------------------
// MFMA bf16 GEMM: C[M,N] = A[M,K](bf16) @ W[N,K](bf16)^T + bias(f32)
// Block tile 128(M) x 64(N), 256 thr = 4 waves (each wave 32M x 64N).
// mfma_f32_16x16x32_bf16 lane maps (HW-verified, guide §3):
//   A frag: A[m=lane&15][k=(lane>>4)*8+j]
//   B frag: W[n=lane&15][k=(lane>>4)*8+j]
//   C/D:    col(n)=lane&15, row(m)=(lane>>4)*4+reg
// flags: 1 = ELU activation; 2 = output bf16 (else fp32)
// ---------------------------------------------------------------------------
__global__ __launch_bounds__(256) void gemm_mfma(
    const ushort_t* __restrict__ A, const ushort_t* __restrict__ W,
    const float* __restrict__ bias, void* __restrict__ Cout,
    int M, int N, int K, int flags)
{
    __shared__ ushort_t As[128 * 136];   // row stride kp = K+8
    __shared__ ushort_t Ws[64 * 136];
    const int t = threadIdx.x;
    const int wave = t >> 6, lane = t & 63;
    const int quad = lane >> 4, l16 = lane & 15;
    const int m0 = blockIdx.y * 128, n0 = blockIdx.x * 64;
    const int kp = K + 8;
    const int ak8 = K >> 3;  // 16B chunks per row

    for (int c = t; c < 128 * ak8; c += 256) {
        int row = c / ak8, col = c - row * ak8;
        *(bf16x8*)&As[row * kp + col * 8] =
            *(const bf16x8*)&A[(size_t)(m0 + row) * K + col * 8];
    }
    for (int c = t; c < 64 * ak8; c += 256) {
        int row = c / ak8, col = c - row * ak8;
        *(bf16x8*)&Ws[row * kp + col * 8] =
            *(const bf16x8*)&W[(size_t)(n0 + row) * K + col * 8];
    }
    __syncthreads();

    f32x4 acc[2][4];
    #pragma unroll
    for (int mt = 0; mt < 2; ++mt)
        #pragma unroll
        for (int nt = 0; nt < 4; ++nt)
            acc[mt][nt] = (f32x4){0.f, 0.f, 0.f, 0.f};

    const ushort_t* arow0 = &As[(wave * 32 + l16) * kp + quad * 8];
    const ushort_t* arow1 = arow0 + 16 * kp;
    const ushort_t* wrow  = &Ws[l16 * kp + quad * 8];

    for (int k0 = 0; k0 < K; k0 += 32) {
        bf16x8 a0 = *(const bf16x8*)(arow0 + k0);
        bf16x8 a1 = *(const bf16x8*)(arow1 + k0);
        #pragma unroll
        for (int nt = 0; nt < 4; ++nt) {
            bf16x8 b = *(const bf16x8*)(wrow + nt * 16 * kp + k0);
            acc[0][nt] = __builtin_amdgcn_mfma_f32_16x16x32_bf16(a0, b, acc[0][nt], 0, 0, 0);
            acc[1][nt] = __builtin_amdgcn_mfma_f32_16x16x32_bf16(a1, b, acc[1][nt], 0, 0, 0);
        }
    }

    #pragma unroll
    for (int mt = 0; mt < 2; ++mt) {
        #pragma unroll
        for (int nt = 0; nt < 4; ++nt) {
            const int n = n0 + nt * 16 + l16;
            const float bs = bias[n];
            #pragma unroll
            for (int r = 0; r < 4; ++r) {
                const int m = m0 + wave * 32 + mt * 16 + quad * 4 + r;
                float v = acc[mt][nt][r] + bs;
                if (flags & 1) v = v > 0.f ? v : expm1f(v);
                if (flags & 2) ((ushort_t*)Cout)[(size_t)m * N + n] = f2b(v);
                else           ((float*)Cout)[(size_t)m * N + n] = v;
            }
        }
    }
}

// ---------------------------------------------------------------------------
// MFMA flash-style attention. Block = (bh, qchunk of 256 rows), 256 threads
// = 4 waves; each wave owns 64 Q rows = 4 m-strips of 16.
//   S-tile:  mfma_16x16x32(Q-frag, K-frag), head-dim 16 zero-padded to k=32.
//            C-layout: lane(q,l16) holds S[m=4q+r][n=l16].
//   softmax: max-free (logits tiny), exp in registers, lsum per-lane partials
//            reduced by shfl_xor(1,2,4,8) over the l16 group at the end.
//   P->PV:   LDS round-trip per wave (private buffer, NO barriers): write
//            P[m][n] as bf16, read back as A-frag (m=l16, k=quad*8+j).
//   PV:      mfma_16x16x32(P-frag, Vt-frag), k = 32 K-rows, full utilization.
//            V staged transposed in LDS so B-frag = one ds_read_b128.
// LDS: K[768][16] 24.0 KB + Vt[16][776] 24.25 KB + P[16][16*40] 20.0 KB
//      = 68.25 KB -> 2 blocks/CU.
// ---------------------------------------------------------------------------
__global__ __launch_bounds__(256) void attention_mfma(
    const ushort_t* __restrict__ qkv, ushort_t* __restrict__ ctx)
{
    __shared__ ushort_t Ks[768 * 16];
    __shared__ ushort_t Vt[16 * 776];
    __shared__ ushort_t Ps[16 * 640];   // [wave*4+strip][16 m][40 stride]

    const int bh = blockIdx.x;
    const int b = bh >> 3, h = bh & 7;
    const int qb = blockIdx.y * 256;
    const int t = threadIdx.x;
    const int wave = t >> 6, lane = t & 63;
    const int quad = lane >> 4, l16 = lane & 15;
    const size_t bbase = (size_t)b * LSEQ * 384;
    const int hoff = h * 16;

    // ---- stage K rows (row-major bf16 [768][16]) and V transposed ----
    for (int idx = t; idx < 1536; idx += 256) {
        int row = idx >> 1, half = idx & 1;
        *(bf16x8*)&Ks[row * 16 + half * 8] =
            *(const bf16x8*)&qkv[bbase + (size_t)row * 384 + EE + hoff + half * 8];
    }
    for (int idx = t; idx < 1536; idx += 256) {
        int row = idx >> 1, half = idx & 1;
        bf16x8 v = *(const bf16x8*)&qkv[bbase + (size_t)row * 384 + 2 * EE + hoff + half * 8];
        #pragma unroll
        for (int j = 0; j < 8; ++j)
            Vt[(half * 8 + j) * 776 + row] = (ushort_t)v[j];
    }

    // ---- Q fragments (registers, quads 2,3 = zero pad of k=32) ----
    const bf16x8 zf = {0, 0, 0, 0, 0, 0, 0, 0};
    bf16x8 qf[4];
    #pragma unroll
    for (int s = 0; s < 4; ++s) {
        qf[s] = zf;
        if (quad < 2) {
            int row = qb + wave * 64 + s * 16 + l16;
            qf[s] = *(const bf16x8*)&qkv[bbase + (size_t)row * 384 + hoff + quad * 8];
        }
    }
    __syncthreads();

    f32x4 ctxacc[4];
    #pragma unroll
    for (int s = 0; s < 4; ++s) ctxacc[s] = (f32x4){0.f, 0.f, 0.f, 0.f};
    float lsum[4][4];
    #pragma unroll
    for (int s = 0; s < 4; ++s)
        #pragma unroll
        for (int r = 0; r < 4; ++r) lsum[s][r] = 0.f;

    const f32x4 zero4 = (f32x4){0.f, 0.f, 0.f, 0.f};

    for (int ch = 0; ch < LSEQ; ch += 32) {
        bf16x8 kf0 = zf, kf1 = zf;
        if (quad < 2) {
            kf0 = *(const bf16x8*)&Ks[(ch + l16) * 16 + quad * 8];
            kf1 = *(const bf16x8*)&Ks[(ch + 16 + l16) * 16 + quad * 8];
        }
        bf16x8 vf = *(const bf16x8*)&Vt[l16 * 776 + ch + quad * 8];

        #pragma unroll
        for (int s = 0; s < 4; ++s) {
            f32x4 s0 = __builtin_amdgcn_mfma_f32_16x16x32_bf16(qf[s], kf0, zero4, 0, 0, 0);
            f32x4 s1 = __builtin_amdgcn_mfma_f32_16x16x32_bf16(qf[s], kf1, zero4, 0, 0, 0);
            ushort_t* pb = &Ps[(wave * 4 + s) * 640];
            #pragma unroll
            for (int r = 0; r < 4; ++r) {
                float p0 = __expf(s0[r] * 0.25f);
                float p1 = __expf(s1[r] * 0.25f);
                lsum[s][r] += p0 + p1;
                pb[(quad * 4 + r) * 40 + l16]      = f2b(p0);
                pb[(quad * 4 + r) * 40 + 16 + l16] = f2b(p1);
            }
            bf16x8 af = *(const bf16x8*)&pb[l16 * 40 + quad * 8];
            ctxacc[s] = __builtin_amdgcn_mfma_f32_16x16x32_bf16(af, vf, ctxacc[s], 0, 0, 0);
        }
    }

    // ---- reduce lsum over the 16 lanes of each quad-group, write ctx ----
    #pragma unroll
    for (int s = 0; s < 4; ++s) {
        #pragma unroll
        for (int r = 0; r < 4; ++r) {
            float v = lsum[s][r];
            v += __shfl_xor(v, 1);
            v += __shfl_xor(v, 2);
            v += __shfl_xor(v, 4);
            v += __shfl_xor(v, 8);
            const float inv = 1.f / v;
            int row = qb + wave * 64 + s * 16 + quad * 4 + r;
            ctx[((size_t)(b * LSEQ + row)) * EE + hoff + l16] =
                f2b(ctxacc[s][r] * inv);
        }
    }
}

// ---------------------------------------------------------------------------
// seq = LayerNorm(seq + branch) * gamma + beta. Writes fp32 + bf16 mirror.
// ---------------------------------------------------------------------------
__global__ __launch_bounds__(128) void ln_residual_kernel(
    float* __restrict__ seq, ushort_t* __restrict__ seq_bf,
    const float* __restrict__ branch,
    const float* __restrict__ gamma, const float* __restrict__ beta)
{
    const int r = blockIdx.x, t = threadIdx.x;
    __shared__ float red[2];
    const int wid = t >> 6, lane = t & 63;

    float v = seq[(size_t)r * EE + t] + branch[(size_t)r * EE + t];
    float s = v;
    #pragma unroll
    for (int off = 32; off; off >>= 1) s += __shfl_down(s, off);
    if (lane == 0) red[wid] = s;
    __syncthreads();
    const float mean = (red[0] + red[1]) * (1.f / 128.f);
    const float d = v - mean;
    float s2 = d * d;
    #pragma unroll
    for (int off = 32; off; off >>= 1) s2 += __shfl_down(s2, off);
    __syncthreads();
    if (lane == 0) red[wid] = s2;
    __syncthreads();
    const float var = (red[0] + red[1]) * (1.f / 128.f);
    const float y = d / sqrtf(var + 1e-5f) * gamma[t] + beta[t];
    seq[(size_t)r * EE + t] = y;
    seq_bf[(size_t)r * EE + t] = f2b(y);
}

// ---------------------------------------------------------------------------
// Final projection, split-K MFMA. out[b,o] = seq_flat[b,:]·out_w[o,:]+out_b[o]
// ---------------------------------------------------------------------------
#define PKC 192
#define PNBLK (KOUT / PKC)   // 512
__global__ __launch_bounds__(256) void out_gemm3(
    const ushort_t* __restrict__ seqbf, const float* __restrict__ out_w,
    float* __restrict__ part)
{
    const int t = threadIdx.x;
    const int wave = t >> 6, lane = t & 63;
    const int quad = lane >> 4, l16 = lane & 15;
    const size_t k0 = (size_t)blockIdx.x * PKC;
    const int n0 = wave * 32;

    f32x4 acc[2][2];
    #pragma unroll
    for (int mt = 0; mt < 2; ++mt)
        #pragma unroll
        for (int nt = 0; nt < 2; ++nt)
            acc[mt][nt] = (f32x4){0.f, 0.f, 0.f, 0.f};

    const ushort_t* a0p = seqbf + (size_t)l16 * KOUT + k0 + quad * 8;
    const ushort_t* a1p = a0p + (size_t)16 * KOUT;
    const float* w0p = out_w + (size_t)(n0 + l16) * KOUT + k0 + quad * 8;
    const float* w1p = w0p + (size_t)16 * KOUT;

    #pragma unroll
    for (int ks = 0; ks < PKC; ks += 32) {
        bf16x8 a0 = *(const bf16x8*)(a0p + ks);
        bf16x8 a1 = *(const bf16x8*)(a1p + ks);
        float4 wa0 = *(const float4*)(w0p + ks);
        float4 wa1 = *(const float4*)(w0p + ks + 4);
        float4 wb0 = *(const float4*)(w1p + ks);
        float4 wb1 = *(const float4*)(w1p + ks + 4);
        bf16x8 bf0, bf1;
        bf0[0] = (short)f2b(wa0.x); bf0[1] = (short)f2b(wa0.y);
        bf0[2] = (short)f2b(wa0.z); bf0[3] = (short)f2b(wa0.w);
        bf0[4] = (short)f2b(wa1.x); bf0[5] = (short)f2b(wa1.y);
        bf0[6] = (short)f2b(wa1.z); bf0[7] = (short)f2b(wa1.w);
        bf1[0] = (short)f2b(wb0.x); bf1[1] = (short)f2b(wb0.y);
        bf1[2] = (short)f2b(wb0.z); bf1[3] = (short)f2b(wb0.w);
        bf1[4] = (short)f2b(wb1.x); bf1[5] = (short)f2b(wb1.y);
        bf1[6] = (short)f2b(wb1.z); bf1[7] = (short)f2b(wb1.w);
        acc[0][0] = __builtin_amdgcn_mfma_f32_16x16x32_bf16(a0, bf0, acc[0][0], 0, 0, 0);
        acc[1][0] = __builtin_amdgcn_mfma_f32_16x16x32_bf16(a1, bf0, acc[1][0], 0, 0, 0);
        acc[0][1] = __builtin_amdgcn_mfma_f32_16x16x32_bf16(a0, bf1, acc[0][1], 0, 0, 0);
        acc[1][1] = __builtin_amdgcn_mfma_f32_16x16x32_bf16(a1, bf1, acc[1][1], 0, 0, 0);
    }

    float* pb = part + (size_t)blockIdx.x * (32 * 128);
    #pragma unroll
    for (int mt = 0; mt < 2; ++mt)
        #pragma unroll
        for (int nt = 0; nt < 2; ++nt)
            #pragma unroll
            for (int r = 0; r < 4; ++r)
                pb[(mt * 16 + quad * 4 + r) * 128 + n0 + nt * 16 + l16] = acc[mt][nt][r];
}

// out[i=b*128+n] = out_b[n] + sum_blk part[blk][b][n]
__global__ __launch_bounds__(256) void out_reduce(
    const float* __restrict__ part, const float* __restrict__ out_b,
    float* __restrict__ out)
{
    const int i = blockIdx.x * 256 + threadIdx.x;   // 0..4095
    const float* p = part + i;
    float s0 = 0.f, s1 = 0.f, s2 = 0.f, s3 = 0.f;
    for (int blk = 0; blk < PNBLK; blk += 4) {
        s0 += p[(size_t)blk * 4096];
        s1 += p[(size_t)(blk + 1) * 4096];
        s2 += p[(size_t)(blk + 2) * 4096];
        s3 += p[(size_t)(blk + 3) * 4096];
    }
    out[i] = out_b[i & (OUTN - 1)] + ((s0 + s1) + (s2 + s3));
}

// ---------------------------------------------------------------------------
extern "C" void kernel_launch(void* const* d_in, const int* in_sizes, int n_in,
                              void* d_out, int out_size, void* d_ws, size_t ws_size,
                              hipStream_t stream)
{
    const float* x          = (const float*)d_in[0];
    const float* prototypes = (const float*)d_in[1];
    const float* emb_w      = (const float*)d_in[2];
    const float* emb_b      = (const float*)d_in[3];
    const float* proj_w     = (const float*)d_in[4];
    const float* proj_b     = (const float*)d_in[5];
    const float* in_proj_w  = (const float*)d_in[6];
    const float* in_proj_b  = (const float*)d_in[7];
    const float* out_proj_w = (const float*)d_in[8];
    const float* out_proj_b = (const float*)d_in[9];
    const float* ln1_s      = (const float*)d_in[10];
    const float* ln1_b      = (const float*)d_in[11];
    const float* ffn_w1     = (const float*)d_in[12];
    const float* ffn_b1     = (const float*)d_in[13];
    const float* ffn_w2     = (const float*)d_in[14];
    const float* ffn_b2     = (const float*)d_in[15];
    const float* ln2_s      = (const float*)d_in[16];
    const float* ln2_b      = (const float*)d_in[17];
    const float* out_w      = (const float*)d_in[18];
    const float* out_b      = (const float*)d_in[19];
    float* out = (float*)d_out;
    char* base = (char*)d_ws;

    // workspace layout (bytes)
    float*    seq    = (float*)base;                        // 12,582,912
    float*    tmp    = (float*)(base + 12582912);           // 12,582,912
    ushort_t* seq_bf = (ushort_t*)(base + 25165824);        //  6,291,456
    ushort_t* qkv_bf = (ushort_t*)(base + 31457280);        // 18,874,368
    ushort_t* ctx_bf = (ushort_t*)(base + 50331648);        //  6,291,456
    ushort_t* h_bf   = (ushort_t*)(base + 56623104);        //  3,145,728
    ushort_t* w_bf   = (ushort_t*)(base + 59768832);        //    655,360 B region
    // part aliases tmp (dead after the last ln_residual): 512*32*128*4 = 8 MB
    float*    part   = (float*)(base + 12582912);

    ushort_t* w_in  = w_bf;            // [2][384][128]
    ushort_t* w_out = w_bf + 98304;    // [2][128][128]
    ushort_t* w_f1  = w_bf + 131072;   // [2][64][128]
    ushort_t* w_f2  = w_bf + 147456;   // [2][128][64]

    cast_bf16_kernel<<<(98304 + 255) / 256, 256, 0, stream>>>(in_proj_w, w_in, 98304);
    cast_bf16_kernel<<<(32768 + 255) / 256, 256, 0, stream>>>(out_proj_w, w_out, 32768);
    cast_bf16_kernel<<<(16384 + 255) / 256, 256, 0, stream>>>(ffn_w1, w_f1, 16384);
    cast_bf16_kernel<<<(16384 + 255) / 256, 256, 0, stream>>>(ffn_w2, w_f2, 16384);

    embed_kernel<<<ROWS, 128, 0, stream>>>(x, prototypes, emb_w, emb_b,
                                           proj_w, proj_b, seq, seq_bf);

    for (int l = 0; l < 2; ++l) {
        // qkv = seq @ Wqkv^T + b   -> bf16 [24576, 384]
        gemm_mfma<<<dim3(6, 192), 256, 0, stream>>>(
            seq_bf, w_in + (size_t)l * 49152, in_proj_b + l * 384,
            qkv_bf, ROWS, 384, 128, 2);
        attention_mfma<<<dim3(BB * HH, 3), 256, 0, stream>>>(qkv_bf, ctx_bf);
        // attn_out = ctx @ Wout^T + b  -> fp32 tmp
        gemm_mfma<<<dim3(2, 192), 256, 0, stream>>>(
            ctx_bf, w_out + (size_t)l * 16384, out_proj_b + l * 128,
            tmp, ROWS, 128, 128, 0);
        ln_residual_kernel<<<ROWS, 128, 0, stream>>>(seq, seq_bf, tmp,
                                                     ln1_s + l * EE, ln1_b + l * EE);
        // h = elu(seq @ W1^T + b1) -> bf16 [24576, 64]
        gemm_mfma<<<dim3(1, 192), 256, 0, stream>>>(
            seq_bf, w_f1 + (size_t)l * 8192, ffn_b1 + l * II,
            h_bf, ROWS, 64, 128, 1 | 2);
        // ffn_out = h @ W2^T + b2  -> fp32 tmp
        gemm_mfma<<<dim3(2, 192), 256, 0, stream>>>(
            h_bf, w_f2 + (size_t)l * 8192, ffn_b2 + l * EE,
            tmp, ROWS, 128, 64, 0);
        ln_residual_kernel<<<ROWS, 128, 0, stream>>>(seq, seq_bf, tmp,
                                                     ln2_s + l * EE, ln2_b + l * EE);
    }

    out_gemm3<<<PNBLK, 256, 0, stream>>>(seq_bf, out_w, part);
    out_reduce<<<BB * OUTN / 256, 256, 0, stream>>>(part, out_b, out);
}

// Round 5
// 432.044 us; speedup vs baseline: 2.0982x; 1.0579x over previous
//
#include <hip/hip_runtime.h>
#include <hip/hip_bf16.h>
#include <math.h>

typedef unsigned short ushort_t;
typedef unsigned int uint_t;

// Problem constants
#define BB 32
#define PP 6
#define DD 96
#define EE 128
#define HH 8
#define II 64
#define KK 32
#define LSEQ 768            // N*D
#define ROWS (BB * LSEQ)    // 24576 token rows
#define OUTN 128
#define KOUT (LSEQ * EE)    // 98304

using bf16x8 = __attribute__((ext_vector_type(8))) short;
using f32x4  = __attribute__((ext_vector_type(4))) float;
using u32x4  = __attribute__((ext_vector_type(4))) uint_t;

__device__ __forceinline__ ushort_t f2b(float f) {
    __hip_bfloat16 h = __float2bfloat16(f);
    return *reinterpret_cast<ushort_t*>(&h);
}
__device__ __forceinline__ float b2f(ushort_t u) {
    __hip_bfloat16 h = *reinterpret_cast<__hip_bfloat16*>(&u);
    return __bfloat162float(h);
}
__device__ __forceinline__ uint_t pack2(float lo, float hi) {
    return (uint_t)f2b(lo) | ((uint_t)f2b(hi) << 16);
}

// ---------------------------------------------------------------------------
// Cast fp32 -> bf16, all four weight tensors in one launch.
// ---------------------------------------------------------------------------
__global__ void cast_all_kernel(
    const float* __restrict__ s0, int n0, const float* __restrict__ s1, int n1,
    const float* __restrict__ s2, int n2, const float* __restrict__ s3, int n3,
    ushort_t* __restrict__ d0, ushort_t* __restrict__ d1,
    ushort_t* __restrict__ d2, ushort_t* __restrict__ d3)
{
    int i = blockIdx.x * 256 + threadIdx.x;
    if (i < n0) { d0[i] = f2b(s0[i]); return; }
    i -= n0;
    if (i < n1) { d1[i] = f2b(s1[i]); return; }
    i -= n1;
    if (i < n2) { d2[i] = f2b(s2[i]); return; }
    i -= n2;
    if (i < n3) { d3[i] = f2b(s3[i]); }
}

// ---------------------------------------------------------------------------
// Embed: row-normalize x, cosine-argmax prototype per (row,d), project both
// through emb_w/proj_w, add positional encoding. One block per row.
// ---------------------------------------------------------------------------
__global__ __launch_bounds__(128) void embed_kernel(
    const float* __restrict__ x, const float* __restrict__ prot,
    const float* __restrict__ emb_w, const float* __restrict__ emb_b,
    const float* __restrict__ proj_w, const float* __restrict__ proj_b,
    float* __restrict__ seq, ushort_t* __restrict__ seq_bf)
{
    const int r = blockIdx.x;      // 0..24575  (= b*L + l)
    const int t = threadIdx.x;     // 0..127
    __shared__ float xrow[PP];
    __shared__ float sel[PP];

    if (t < PP) xrow[t] = x[r * PP + t];
    __syncthreads();

    float nx = 0.f;
    #pragma unroll
    for (int p = 0; p < PP; ++p) nx += xrow[p] * xrow[p];
    const float xinv = 1.f / fmaxf(sqrtf(nx), 1e-12f);

    const int d = r % DD;
    if (t < KK) {
        const float* pr = prot + (d * KK + t) * PP;
        float pp[PP];
        float np2 = 0.f;
        #pragma unroll
        for (int p = 0; p < PP; ++p) { pp[p] = pr[p]; np2 += pp[p] * pp[p]; }
        const float pinv = 1.f / fmaxf(sqrtf(np2), 1e-12f);
        float dot = 0.f;
        #pragma unroll
        for (int p = 0; p < PP; ++p) dot += xrow[p] * pp[p];
        float sim = dot * xinv * pinv;
        int k = t;
        #pragma unroll
        for (int off = 16; off; off >>= 1) {
            float osim = __shfl_down(sim, off);
            int   ok   = __shfl_down(k, off);
            if (osim > sim || (osim == sim && ok < k)) { sim = osim; k = ok; }
        }
        k = __shfl(k, 0);
        if (t == k) {
            #pragma unroll
            for (int p = 0; p < PP; ++p) sel[p] = pp[p] * pinv;
        }
    }
    __syncthreads();

    float acc = emb_b[t] + proj_b[t];
    #pragma unroll
    for (int p = 0; p < PP; ++p) acc = fmaf(xrow[p], emb_w[t * PP + p], acc);
    #pragma unroll
    for (int p = 0; p < PP; ++p) acc = fmaf(sel[p], proj_w[t * PP + p], acc);

    const int lpos = r % LSEQ;
    const float twoj = (float)((t >> 1) * 2);
    const float div = __expf(twoj * (-9.210340371976184f / 128.0f));
    const float ang = (float)lpos * div;
    const float pe = (t & 1) ? cosf(ang) : sinf(ang);
    const float v = acc + pe;
    seq[(size_t)r * EE + t] = v;
    seq_bf[(size_t)r * EE + t] = f2b(v);
}

// ---------------------------------------------------------------------------
// MFMA bf16 GEMM: C[M,N] = A[M,K](bf16) @ W[N,K](bf16)^T + bias(f32)
// Block tile 128(M) x 64(N), 256 thr = 4 waves (each wave 32M x 64N).
// flags: 1 = ELU activation; 2 = output bf16 (else fp32)
// ---------------------------------------------------------------------------
__global__ __launch_bounds__(256) void gemm_mfma(
    const ushort_t* __restrict__ A, const ushort_t* __restrict__ W,
    const float* __restrict__ bias, void* __restrict__ Cout,
    int M, int N, int K, int flags)
{
    __shared__ ushort_t As[128 * 136];   // row stride kp = K+8
    __shared__ ushort_t Ws[64 * 136];
    const int t = threadIdx.x;
    const int wave = t >> 6, lane = t & 63;
    const int quad = lane >> 4, l16 = lane & 15;
    const int m0 = blockIdx.y * 128, n0 = blockIdx.x * 64;
    const int kp = K + 8;
    const int ak8 = K >> 3;  // 16B chunks per row

    for (int c = t; c < 128 * ak8; c += 256) {
        int row = c / ak8, col = c - row * ak8;
        *(bf16x8*)&As[row * kp + col * 8] =
            *(const bf16x8*)&A[(size_t)(m0 + row) * K + col * 8];
    }
    for (int c = t; c < 64 * ak8; c += 256) {
        int row = c / ak8, col = c - row * ak8;
        *(bf16x8*)&Ws[row * kp + col * 8] =
            *(const bf16x8*)&W[(size_t)(n0 + row) * K + col * 8];
    }
    __syncthreads();

    f32x4 acc[2][4];
    #pragma unroll
    for (int mt = 0; mt < 2; ++mt)
        #pragma unroll
        for (int nt = 0; nt < 4; ++nt)
            acc[mt][nt] = (f32x4){0.f, 0.f, 0.f, 0.f};

    const ushort_t* arow0 = &As[(wave * 32 + l16) * kp + quad * 8];
    const ushort_t* arow1 = arow0 + 16 * kp;
    const ushort_t* wrow  = &Ws[l16 * kp + quad * 8];

    for (int k0 = 0; k0 < K; k0 += 32) {
        bf16x8 a0 = *(const bf16x8*)(arow0 + k0);
        bf16x8 a1 = *(const bf16x8*)(arow1 + k0);
        #pragma unroll
        for (int nt = 0; nt < 4; ++nt) {
            bf16x8 b = *(const bf16x8*)(wrow + nt * 16 * kp + k0);
            acc[0][nt] = __builtin_amdgcn_mfma_f32_16x16x32_bf16(a0, b, acc[0][nt], 0, 0, 0);
            acc[1][nt] = __builtin_amdgcn_mfma_f32_16x16x32_bf16(a1, b, acc[1][nt], 0, 0, 0);
        }
    }

    #pragma unroll
    for (int mt = 0; mt < 2; ++mt) {
        #pragma unroll
        for (int nt = 0; nt < 4; ++nt) {
            const int n = n0 + nt * 16 + l16;
            const float bs = bias[n];
            #pragma unroll
            for (int r = 0; r < 4; ++r) {
                const int m = m0 + wave * 32 + mt * 16 + quad * 4 + r;
                float v = acc[mt][nt][r] + bs;
                if (flags & 1) v = v > 0.f ? v : expm1f(v);
                if (flags & 2) ((ushort_t*)Cout)[(size_t)m * N + n] = f2b(v);
                else           ((float*)Cout)[(size_t)m * N + n] = v;
            }
        }
    }
}

// ---------------------------------------------------------------------------
// MFMA flash attention, S^T formulation (no LDS P round-trip).
// Block = (bh, qchunk of 256 rows), 256 thr = 4 waves; wave owns 64 q rows
// = 4 strips of 16.
//   S^T tile: mfma(K-frag, Q-frag) -> C: col=q (l16), row=key (quad*4+r).
//             (A and B frags have identical per-lane layouts, so swapping
//              operands transposes the output; head-dim 16 zero-pad to k=32.)
//   softmax:  all 8 exps of a lane share one q-column -> lsum is a scalar
//             per lane; final reduce = shfl_xor(16) + shfl_xor(32).
//   P^T ->    B-frag (keys quad*8+j, col l16) built by register shuffle:
//             pack exp pairs to u32; dest quad takes regs of source quads
//             2*(quad&1), 2*(quad&1)+1 of tile (quad>=2). 8 shfl + 4 sel.
//   PV:       mfma(V^T-frag, P^T-frag) accumulates O^T (row=dim, col=q).
// LDS: Ks[768][16] 24.0 KB + Vt[16][792] 24.75 KB = 48.75 KB -> 3 blocks/CU.
// ---------------------------------------------------------------------------
#define VTS 792   // Vt row stride (ushorts), multiple of 8 for b128 alignment
__global__ __launch_bounds__(256, 3) void attention_mfma(
    const ushort_t* __restrict__ qkv, ushort_t* __restrict__ ctx)
{
    __shared__ ushort_t Ks[768 * 16];
    __shared__ ushort_t Vt[16 * VTS];

    const int bh = blockIdx.x;
    const int b = bh >> 3, h = bh & 7;
    const int qb = blockIdx.y * 256;
    const int t = threadIdx.x;
    const int wave = t >> 6, lane = t & 63;
    const int quad = lane >> 4, l16 = lane & 15;
    const size_t bbase = (size_t)b * LSEQ * 384;
    const int hoff = h * 16;

    // ---- stage K rows (row-major bf16 [768][16]) and V transposed ----
    for (int idx = t; idx < 1536; idx += 256) {
        int row = idx >> 1, half = idx & 1;
        *(bf16x8*)&Ks[row * 16 + half * 8] =
            *(const bf16x8*)&qkv[bbase + (size_t)row * 384 + EE + hoff + half * 8];
    }
    for (int idx = t; idx < 1536; idx += 256) {
        int row = idx >> 1, half = idx & 1;
        bf16x8 v = *(const bf16x8*)&qkv[bbase + (size_t)row * 384 + 2 * EE + hoff + half * 8];
        #pragma unroll
        for (int j = 0; j < 8; ++j)
            Vt[(half * 8 + j) * VTS + row] = (ushort_t)v[j];
    }

    // ---- Q fragments (registers; quads 2,3 = zero pad of k=32) ----
    const bf16x8 zf = {0, 0, 0, 0, 0, 0, 0, 0};
    bf16x8 qf[4];
    #pragma unroll
    for (int s = 0; s < 4; ++s) {
        qf[s] = zf;
        if (quad < 2) {
            int row = qb + wave * 64 + s * 16 + l16;
            qf[s] = *(const bf16x8*)&qkv[bbase + (size_t)row * 384 + hoff + quad * 8];
        }
    }
    __syncthreads();

    f32x4 ctxacc[4];
    #pragma unroll
    for (int s = 0; s < 4; ++s) ctxacc[s] = (f32x4){0.f, 0.f, 0.f, 0.f};
    float lsum[4] = {0.f, 0.f, 0.f, 0.f};

    const f32x4 zero4 = (f32x4){0.f, 0.f, 0.f, 0.f};
    const int srcA = ((quad & 1) << 5) | l16;   // lanes of source quads 2*(quad&1)
    const int srcB = srcA + 16;                 // and 2*(quad&1)+1

    for (int ch = 0; ch < LSEQ; ch += 32) {
        bf16x8 kf0 = zf, kf1 = zf;
        if (quad < 2) {
            kf0 = *(const bf16x8*)&Ks[(ch + l16) * 16 + quad * 8];
            kf1 = *(const bf16x8*)&Ks[(ch + 16 + l16) * 16 + quad * 8];
        }
        bf16x8 vf = *(const bf16x8*)&Vt[l16 * VTS + ch + quad * 8];

        #pragma unroll
        for (int s = 0; s < 4; ++s) {
            // S^T tiles: keys 0-15 and 16-31 of this chunk, q col = l16
            f32x4 s0 = __builtin_amdgcn_mfma_f32_16x16x32_bf16(kf0, qf[s], zero4, 0, 0, 0);
            f32x4 s1 = __builtin_amdgcn_mfma_f32_16x16x32_bf16(kf1, qf[s], zero4, 0, 0, 0);
            float e00 = __expf(s0[0] * 0.25f), e01 = __expf(s0[1] * 0.25f);
            float e02 = __expf(s0[2] * 0.25f), e03 = __expf(s0[3] * 0.25f);
            float e10 = __expf(s1[0] * 0.25f), e11 = __expf(s1[1] * 0.25f);
            float e12 = __expf(s1[2] * 0.25f), e13 = __expf(s1[3] * 0.25f);
            lsum[s] += ((e00 + e01) + (e02 + e03)) + ((e10 + e11) + (e12 + e13));
            // pack: keys (quad*4+0, +1) and (+2, +3) per tile
            uint_t p00 = pack2(e00, e01), p01 = pack2(e02, e03);
            uint_t p10 = pack2(e10, e11), p11 = pack2(e12, e13);
            // gather B-frag: dest lane needs keys quad*8..quad*8+7, col l16
            uint_t a0t0 = __shfl(p00, srcA), a1t0 = __shfl(p01, srcA);
            uint_t a2t0 = __shfl(p00, srcB), a3t0 = __shfl(p01, srcB);
            uint_t a0t1 = __shfl(p10, srcA), a1t1 = __shfl(p11, srcA);
            uint_t a2t1 = __shfl(p10, srcB), a3t1 = __shfl(p11, srcB);
            u32x4 xx;
            xx[0] = (quad < 2) ? a0t0 : a0t1;
            xx[1] = (quad < 2) ? a1t0 : a1t1;
            xx[2] = (quad < 2) ? a2t0 : a2t1;
            xx[3] = (quad < 2) ? a3t0 : a3t1;
            bf16x8 pf = __builtin_bit_cast(bf16x8, xx);
            // PV: O^T[dim][q] += V^T[dim][keys] * P^T[keys][q]
            ctxacc[s] = __builtin_amdgcn_mfma_f32_16x16x32_bf16(vf, pf, ctxacc[s], 0, 0, 0);
        }
    }

    // ---- normalize (row sum over 4 quads sharing l16) and write O ----
    #pragma unroll
    for (int s = 0; s < 4; ++s) {
        float tot = lsum[s];
        tot += __shfl_xor(tot, 16);
        tot += __shfl_xor(tot, 32);
        const float inv = 1.f / tot;
        const int row = qb + wave * 64 + s * 16 + l16;   // q row
        uint_t lo = pack2(ctxacc[s][0] * inv, ctxacc[s][1] * inv);
        uint_t hi = pack2(ctxacc[s][2] * inv, ctxacc[s][3] * inv);
        uint2 w2; w2.x = lo; w2.y = hi;
        *(uint2*)&ctx[((size_t)(b * LSEQ + row)) * EE + hoff + quad * 4] = w2;
    }
}

// ---------------------------------------------------------------------------
// seq = LayerNorm(seq + branch) * gamma + beta. Writes fp32 + bf16 mirror.
// ---------------------------------------------------------------------------
__global__ __launch_bounds__(128) void ln_residual_kernel(
    float* __restrict__ seq, ushort_t* __restrict__ seq_bf,
    const float* __restrict__ branch,
    const float* __restrict__ gamma, const float* __restrict__ beta)
{
    const int r = blockIdx.x, t = threadIdx.x;
    __shared__ float red[2];
    const int wid = t >> 6, lane = t & 63;

    float v = seq[(size_t)r * EE + t] + branch[(size_t)r * EE + t];
    float s = v;
    #pragma unroll
    for (int off = 32; off; off >>= 1) s += __shfl_down(s, off);
    if (lane == 0) red[wid] = s;
    __syncthreads();
    const float mean = (red[0] + red[1]) * (1.f / 128.f);
    const float d = v - mean;
    float s2 = d * d;
    #pragma unroll
    for (int off = 32; off; off >>= 1) s2 += __shfl_down(s2, off);
    __syncthreads();
    if (lane == 0) red[wid] = s2;
    __syncthreads();
    const float var = (red[0] + red[1]) * (1.f / 128.f);
    const float y = d / sqrtf(var + 1e-5f) * gamma[t] + beta[t];
    seq[(size_t)r * EE + t] = y;
    seq_bf[(size_t)r * EE + t] = f2b(y);
}

// ---------------------------------------------------------------------------
// Final projection, split-K MFMA. out[b,o] = seq_flat[b,:]·out_w[o,:]+out_b[o]
// ---------------------------------------------------------------------------
#define PKC 192
#define PNBLK (KOUT / PKC)   // 512
__global__ __launch_bounds__(256) void out_gemm3(
    const ushort_t* __restrict__ seqbf, const float* __restrict__ out_w,
    float* __restrict__ part)
{
    const int t = threadIdx.x;
    const int wave = t >> 6, lane = t & 63;
    const int quad = lane >> 4, l16 = lane & 15;
    const size_t k0 = (size_t)blockIdx.x * PKC;
    const int n0 = wave * 32;

    f32x4 acc[2][2];
    #pragma unroll
    for (int mt = 0; mt < 2; ++mt)
        #pragma unroll
        for (int nt = 0; nt < 2; ++nt)
            acc[mt][nt] = (f32x4){0.f, 0.f, 0.f, 0.f};

    const ushort_t* a0p = seqbf + (size_t)l16 * KOUT + k0 + quad * 8;
    const ushort_t* a1p = a0p + (size_t)16 * KOUT;
    const float* w0p = out_w + (size_t)(n0 + l16) * KOUT + k0 + quad * 8;
    const float* w1p = w0p + (size_t)16 * KOUT;

    #pragma unroll
    for (int ks = 0; ks < PKC; ks += 32) {
        bf16x8 a0 = *(const bf16x8*)(a0p + ks);
        bf16x8 a1 = *(const bf16x8*)(a1p + ks);
        float4 wa0 = *(const float4*)(w0p + ks);
        float4 wa1 = *(const float4*)(w0p + ks + 4);
        float4 wb0 = *(const float4*)(w1p + ks);
        float4 wb1 = *(const float4*)(w1p + ks + 4);
        bf16x8 bf0, bf1;
        bf0[0] = (short)f2b(wa0.x); bf0[1] = (short)f2b(wa0.y);
        bf0[2] = (short)f2b(wa0.z); bf0[3] = (short)f2b(wa0.w);
        bf0[4] = (short)f2b(wa1.x); bf0[5] = (short)f2b(wa1.y);
        bf0[6] = (short)f2b(wa1.z); bf0[7] = (short)f2b(wa1.w);
        bf1[0] = (short)f2b(wb0.x); bf1[1] = (short)f2b(wb0.y);
        bf1[2] = (short)f2b(wb0.z); bf1[3] = (short)f2b(wb0.w);
        bf1[4] = (short)f2b(wb1.x); bf1[5] = (short)f2b(wb1.y);
        bf1[6] = (short)f2b(wb1.z); bf1[7] = (short)f2b(wb1.w);
        acc[0][0] = __builtin_amdgcn_mfma_f32_16x16x32_bf16(a0, bf0, acc[0][0], 0, 0, 0);
        acc[1][0] = __builtin_amdgcn_mfma_f32_16x16x32_bf16(a1, bf0, acc[1][0], 0, 0, 0);
        acc[0][1] = __builtin_amdgcn_mfma_f32_16x16x32_bf16(a0, bf1, acc[0][1], 0, 0, 0);
        acc[1][1] = __builtin_amdgcn_mfma_f32_16x16x32_bf16(a1, bf1, acc[1][1], 0, 0, 0);
    }

    float* pb = part + (size_t)blockIdx.x * (32 * 128);
    #pragma unroll
    for (int mt = 0; mt < 2; ++mt)
        #pragma unroll
        for (int nt = 0; nt < 2; ++nt)
            #pragma unroll
            for (int r = 0; r < 4; ++r)
                pb[(mt * 16 + quad * 4 + r) * 128 + n0 + nt * 16 + l16] = acc[mt][nt][r];
}

// out[i=b*128+n] = out_b[n] + sum_blk part[blk][b][n]
__global__ __launch_bounds__(256) void out_reduce(
    const float* __restrict__ part, const float* __restrict__ out_b,
    float* __restrict__ out)
{
    const int i = blockIdx.x * 256 + threadIdx.x;   // 0..4095
    const float* p = part + i;
    float s0 = 0.f, s1 = 0.f, s2 = 0.f, s3 = 0.f;
    for (int blk = 0; blk < PNBLK; blk += 4) {
        s0 += p[(size_t)blk * 4096];
        s1 += p[(size_t)(blk + 1) * 4096];
        s2 += p[(size_t)(blk + 2) * 4096];
        s3 += p[(size_t)(blk + 3) * 4096];
    }
    out[i] = out_b[i & (OUTN - 1)] + ((s0 + s1) + (s2 + s3));
}

// ---------------------------------------------------------------------------
extern "C" void kernel_launch(void* const* d_in, const int* in_sizes, int n_in,
                              void* d_out, int out_size, void* d_ws, size_t ws_size,
                              hipStream_t stream)
{
    const float* x          = (const float*)d_in[0];
    const float* prototypes = (const float*)d_in[1];
    const float* emb_w      = (const float*)d_in[2];
    const float* emb_b      = (const float*)d_in[3];
    const float* proj_w     = (const float*)d_in[4];
    const float* proj_b     = (const float*)d_in[5];
    const float* in_proj_w  = (const float*)d_in[6];
    const float* in_proj_b  = (const float*)d_in[7];
    const float* out_proj_w = (const float*)d_in[8];
    const float* out_proj_b = (const float*)d_in[9];
    const float* ln1_s      = (const float*)d_in[10];
    const float* ln1_b      = (const float*)d_in[11];
    const float* ffn_w1     = (const float*)d_in[12];
    const float* ffn_b1     = (const float*)d_in[13];
    const float* ffn_w2     = (const float*)d_in[14];
    const float* ffn_b2     = (const float*)d_in[15];
    const float* ln2_s      = (const float*)d_in[16];
    const float* ln2_b      = (const float*)d_in[17];
    const float* out_w      = (const float*)d_in[18];
    const float* out_b      = (const float*)d_in[19];
    float* out = (float*)d_out;
    char* base = (char*)d_ws;

    // workspace layout (bytes)
    float*    seq    = (float*)base;                        // 12,582,912
    float*    tmp    = (float*)(base + 12582912);           // 12,582,912
    ushort_t* seq_bf = (ushort_t*)(base + 25165824);        //  6,291,456
    ushort_t* qkv_bf = (ushort_t*)(base + 31457280);        // 18,874,368
    ushort_t* ctx_bf = (ushort_t*)(base + 50331648);        //  6,291,456
    ushort_t* h_bf   = (ushort_t*)(base + 56623104);        //  3,145,728
    ushort_t* w_bf   = (ushort_t*)(base + 59768832);        //    655,360 B region
    // part aliases tmp (dead after the last ln_residual): 512*32*128*4 = 8 MB
    float*    part   = (float*)(base + 12582912);

    ushort_t* w_in  = w_bf;            // [2][384][128]
    ushort_t* w_out = w_bf + 98304;    // [2][128][128]
    ushort_t* w_f1  = w_bf + 131072;   // [2][64][128]
    ushort_t* w_f2  = w_bf + 147456;   // [2][128][64]

    cast_all_kernel<<<(163840 + 255) / 256, 256, 0, stream>>>(
        in_proj_w, 98304, out_proj_w, 32768, ffn_w1, 16384, ffn_w2, 16384,
        w_in, w_out, w_f1, w_f2);

    embed_kernel<<<ROWS, 128, 0, stream>>>(x, prototypes, emb_w, emb_b,
                                           proj_w, proj_b, seq, seq_bf);

    for (int l = 0; l < 2; ++l) {
        // qkv = seq @ Wqkv^T + b   -> bf16 [24576, 384]
        gemm_mfma<<<dim3(6, 192), 256, 0, stream>>>(
            seq_bf, w_in + (size_t)l * 49152, in_proj_b + l * 384,
            qkv_bf, ROWS, 384, 128, 2);
        attention_mfma<<<dim3(BB * HH, 3), 256, 0, stream>>>(qkv_bf, ctx_bf);
        // attn_out = ctx @ Wout^T + b  -> fp32 tmp
        gemm_mfma<<<dim3(2, 192), 256, 0, stream>>>(
            ctx_bf, w_out + (size_t)l * 16384, out_proj_b + l * 128,
            tmp, ROWS, 128, 128, 0);
        ln_residual_kernel<<<ROWS, 128, 0, stream>>>(seq, seq_bf, tmp,
                                                     ln1_s + l * EE, ln1_b + l * EE);
        // h = elu(seq @ W1^T + b1) -> bf16 [24576, 64]
        gemm_mfma<<<dim3(1, 192), 256, 0, stream>>>(
            seq_bf, w_f1 + (size_t)l * 8192, ffn_b1 + l * II,
            h_bf, ROWS, 64, 128, 1 | 2);
        // ffn_out = h @ W2^T + b2  -> fp32 tmp
        gemm_mfma<<<dim3(2, 192), 256, 0, stream>>>(
            h_bf, w_f2 + (size_t)l * 8192, ffn_b2 + l * EE,
            tmp, ROWS, 128, 64, 0);
        ln_residual_kernel<<<ROWS, 128, 0, stream>>>(seq, seq_bf, tmp,
                                                     ln2_s + l * EE, ln2_b + l * EE);
    }

    out_gemm3<<<PNBLK, 256, 0, stream>>>(seq_bf, out_w, part);
    out_reduce<<<BB * OUTN / 256, 256, 0, stream>>>(part, out_b, out);
}

// Round 6
// 402.781 us; speedup vs baseline: 2.2506x; 1.0727x over previous
//
#include <hip/hip_runtime.h>
#include <hip/hip_bf16.h>
#include <math.h>

typedef unsigned short ushort_t;
typedef unsigned int uint_t;

// Problem constants
#define BB 32
#define PP 6
#define DD 96
#define EE 128
#define HH 8
#define II 64
#define KK 32
#define LSEQ 768            // N*D
#define ROWS (BB * LSEQ)    // 24576 token rows
#define OUTN 128
#define KOUT (LSEQ * EE)    // 98304

using bf16x8 = __attribute__((ext_vector_type(8))) short;
using bf16x4 = __attribute__((ext_vector_type(4))) short;
using f32x4  = __attribute__((ext_vector_type(4))) float;

__device__ __forceinline__ ushort_t f2b(float f) {
    __hip_bfloat16 h = __float2bfloat16(f);
    return *reinterpret_cast<ushort_t*>(&h);
}
__device__ __forceinline__ uint_t pack2(float lo, float hi) {
    return (uint_t)f2b(lo) | ((uint_t)f2b(hi) << 16);
}

// ---------------------------------------------------------------------------
// Cast fp32 -> bf16, all four weight tensors in one launch.
// ---------------------------------------------------------------------------
__global__ void cast_all_kernel(
    const float* __restrict__ s0, int n0, const float* __restrict__ s1, int n1,
    const float* __restrict__ s2, int n2, const float* __restrict__ s3, int n3,
    ushort_t* __restrict__ d0, ushort_t* __restrict__ d1,
    ushort_t* __restrict__ d2, ushort_t* __restrict__ d3)
{
    int i = blockIdx.x * 256 + threadIdx.x;
    if (i < n0) { d0[i] = f2b(s0[i]); return; }
    i -= n0;
    if (i < n1) { d1[i] = f2b(s1[i]); return; }
    i -= n1;
    if (i < n2) { d2[i] = f2b(s2[i]); return; }
    i -= n2;
    if (i < n3) { d3[i] = f2b(s3[i]); }
}

// ---------------------------------------------------------------------------
// Embed: row-normalize x, cosine-argmax prototype per (row,d), project both
// through emb_w/proj_w, add positional encoding. One block per row.
// ---------------------------------------------------------------------------
__global__ __launch_bounds__(128) void embed_kernel(
    const float* __restrict__ x, const float* __restrict__ prot,
    const float* __restrict__ emb_w, const float* __restrict__ emb_b,
    const float* __restrict__ proj_w, const float* __restrict__ proj_b,
    float* __restrict__ seq, ushort_t* __restrict__ seq_bf)
{
    const int r = blockIdx.x;      // 0..24575  (= b*L + l)
    const int t = threadIdx.x;     // 0..127
    __shared__ float xrow[PP];
    __shared__ float sel[PP];

    if (t < PP) xrow[t] = x[r * PP + t];
    __syncthreads();

    float nx = 0.f;
    #pragma unroll
    for (int p = 0; p < PP; ++p) nx += xrow[p] * xrow[p];
    const float xinv = 1.f / fmaxf(sqrtf(nx), 1e-12f);

    const int d = r % DD;
    if (t < KK) {
        const float* pr = prot + (d * KK + t) * PP;
        float pp[PP];
        float np2 = 0.f;
        #pragma unroll
        for (int p = 0; p < PP; ++p) { pp[p] = pr[p]; np2 += pp[p] * pp[p]; }
        const float pinv = 1.f / fmaxf(sqrtf(np2), 1e-12f);
        float dot = 0.f;
        #pragma unroll
        for (int p = 0; p < PP; ++p) dot += xrow[p] * pp[p];
        float sim = dot * xinv * pinv;
        int k = t;
        #pragma unroll
        for (int off = 16; off; off >>= 1) {
            float osim = __shfl_down(sim, off);
            int   ok   = __shfl_down(k, off);
            if (osim > sim || (osim == sim && ok < k)) { sim = osim; k = ok; }
        }
        k = __shfl(k, 0);
        if (t == k) {
            #pragma unroll
            for (int p = 0; p < PP; ++p) sel[p] = pp[p] * pinv;
        }
    }
    __syncthreads();

    float acc = emb_b[t] + proj_b[t];
    #pragma unroll
    for (int p = 0; p < PP; ++p) acc = fmaf(xrow[p], emb_w[t * PP + p], acc);
    #pragma unroll
    for (int p = 0; p < PP; ++p) acc = fmaf(sel[p], proj_w[t * PP + p], acc);

    const int lpos = r % LSEQ;
    const float twoj = (float)((t >> 1) * 2);
    const float div = __expf(twoj * (-9.210340371976184f / 128.0f));
    const float ang = (float)lpos * div;
    const float pe = (t & 1) ? cosf(ang) : sinf(ang);
    const float v = acc + pe;
    seq[(size_t)r * EE + t] = v;
    seq_bf[(size_t)r * EE + t] = f2b(v);
}

// ---------------------------------------------------------------------------
// MFMA bf16 GEMM: C[M,N] = A[M,K](bf16) @ W[N,K](bf16)^T + bias(f32)
// Block tile 128(M) x 64(N), 256 thr = 4 waves.
// flags: 1 = ELU; 2 = output bf16; 4 = scale cols n<128 by 0.25 (Q pre-scale)
// ---------------------------------------------------------------------------
__global__ __launch_bounds__(256) void gemm_mfma(
    const ushort_t* __restrict__ A, const ushort_t* __restrict__ W,
    const float* __restrict__ bias, void* __restrict__ Cout,
    int M, int N, int K, int flags)
{
    __shared__ ushort_t As[128 * 136];   // row stride kp = K+8
    __shared__ ushort_t Ws[64 * 136];
    const int t = threadIdx.x;
    const int wave = t >> 6, lane = t & 63;
    const int quad = lane >> 4, l16 = lane & 15;
    const int m0 = blockIdx.y * 128, n0 = blockIdx.x * 64;
    const int kp = K + 8;
    const int ak8 = K >> 3;  // 16B chunks per row

    for (int c = t; c < 128 * ak8; c += 256) {
        int row = c / ak8, col = c - row * ak8;
        *(bf16x8*)&As[row * kp + col * 8] =
            *(const bf16x8*)&A[(size_t)(m0 + row) * K + col * 8];
    }
    for (int c = t; c < 64 * ak8; c += 256) {
        int row = c / ak8, col = c - row * ak8;
        *(bf16x8*)&Ws[row * kp + col * 8] =
            *(const bf16x8*)&W[(size_t)(n0 + row) * K + col * 8];
    }
    __syncthreads();

    f32x4 acc[2][4];
    #pragma unroll
    for (int mt = 0; mt < 2; ++mt)
        #pragma unroll
        for (int nt = 0; nt < 4; ++nt)
            acc[mt][nt] = (f32x4){0.f, 0.f, 0.f, 0.f};

    const ushort_t* arow0 = &As[(wave * 32 + l16) * kp + quad * 8];
    const ushort_t* arow1 = arow0 + 16 * kp;
    const ushort_t* wrow  = &Ws[l16 * kp + quad * 8];

    for (int k0 = 0; k0 < K; k0 += 32) {
        bf16x8 a0 = *(const bf16x8*)(arow0 + k0);
        bf16x8 a1 = *(const bf16x8*)(arow1 + k0);
        #pragma unroll
        for (int nt = 0; nt < 4; ++nt) {
            bf16x8 b = *(const bf16x8*)(wrow + nt * 16 * kp + k0);
            acc[0][nt] = __builtin_amdgcn_mfma_f32_16x16x32_bf16(a0, b, acc[0][nt], 0, 0, 0);
            acc[1][nt] = __builtin_amdgcn_mfma_f32_16x16x32_bf16(a1, b, acc[1][nt], 0, 0, 0);
        }
    }

    #pragma unroll
    for (int mt = 0; mt < 2; ++mt) {
        #pragma unroll
        for (int nt = 0; nt < 4; ++nt) {
            const int n = n0 + nt * 16 + l16;
            const float bs = bias[n];
            #pragma unroll
            for (int r = 0; r < 4; ++r) {
                const int m = m0 + wave * 32 + mt * 16 + quad * 4 + r;
                float v = acc[mt][nt][r] + bs;
                if (flags & 1) v = v > 0.f ? v : expm1f(v);
                if ((flags & 4) && n < EE) v *= 0.25f;   // Q pre-scale
                if (flags & 2) ((ushort_t*)Cout)[(size_t)m * N + n] = f2b(v);
                else           ((float*)Cout)[(size_t)m * N + n] = v;
            }
        }
    }
}

// ---------------------------------------------------------------------------
// MFMA flash attention v3 — 16x16x16 mfma, zero cross-lane movement.
// Block = (bh, qchunk of 256 rows), 256 thr = 4 waves; wave owns 64 q rows
// = 4 strips of 16.
//   S^T:  mfma_16x16x16(K-frag, Q-frag): A=K[key=l16][dim=quad*4+j] (GLOBAL
//         b64 read, 32B/row segments, L2-hot), B=Q[q=l16][dim=quad*4+j]
//         (global b64, once). C: lane = S^T[key=quad*4+r][q=l16].
//   exp:  in-register; lsum per lane is partial over its 4 keys for q=l16.
//   PV:   the exp'd C-regs ARE the PV B-frag (P^T[key=quad*4+j][q=l16]).
//         A = V^T[dim=l16][key=quad*4+j] from LDS Vt (b64). Accumulates
//         O^T[dim=quad*4+r][q=l16].
//   norm: lsum xor16+xor32 -> tot for q=l16, matches O^T col. uint2 store.
// LDS: Vt only, 16 x 792 x 2B = 25.3 KB. No Ks array, no P round-trip,
// no bpermutes -> LDS-pipe ops per chunk-strip drop ~10x vs round 5.
// Q must be pre-scaled by 0.25 (gemm_mfma flag 4).
// ---------------------------------------------------------------------------
#define VTS 792   // Vt row stride (ushorts): 396 dwords == 12 mod 32 -> 2-way
__global__ __launch_bounds__(256) void attention_mfma(
    const ushort_t* __restrict__ qkv, ushort_t* __restrict__ ctx)
{
    __shared__ ushort_t Vt[16 * VTS];

    const int bh = blockIdx.x;
    const int b = bh >> 3, h = bh & 7;
    const int qb = blockIdx.y * 256;
    const int t = threadIdx.x;
    const int wave = t >> 6, lane = t & 63;
    const int quad = lane >> 4, l16 = lane & 15;
    const size_t bbase = (size_t)b * LSEQ * 384;
    const int hoff = h * 16;

    // ---- stage V transposed ----
    for (int idx = t; idx < 1536; idx += 256) {
        int row = idx >> 1, half = idx & 1;
        bf16x8 v = *(const bf16x8*)&qkv[bbase + (size_t)row * 384 + 2 * EE + hoff + half * 8];
        #pragma unroll
        for (int j = 0; j < 8; ++j)
            Vt[(half * 8 + j) * VTS + row] = (ushort_t)v[j];
    }

    // ---- Q fragments: B[k=dim quad*4+j][n=q l16] = Q[q][dim] ----
    bf16x4 qf[4];
    #pragma unroll
    for (int s = 0; s < 4; ++s) {
        int row = qb + wave * 64 + s * 16 + l16;
        qf[s] = *(const bf16x4*)&qkv[bbase + (size_t)row * 384 + hoff + quad * 4];
    }
    __syncthreads();

    f32x4 oacc[4];
    #pragma unroll
    for (int s = 0; s < 4; ++s) oacc[s] = (f32x4){0.f, 0.f, 0.f, 0.f};
    float lsum[4] = {0.f, 0.f, 0.f, 0.f};
    const f32x4 zero4 = (f32x4){0.f, 0.f, 0.f, 0.f};

    const ushort_t* kbase = qkv + bbase + EE + hoff + quad * 4;

    for (int ch = 0; ch < LSEQ; ch += 16) {
        // K A-frag: K[key=ch+l16][dim=quad*4..+3]  (global, 8B/lane)
        bf16x4 kf = *(const bf16x4*)&kbase[(size_t)(ch + l16) * 384];
        // V^T A-frag: V^T[dim=l16][keys ch+quad*4..+3]  (LDS b64)
        bf16x4 vf = *(const bf16x4*)&Vt[l16 * VTS + ch + quad * 4];

        #pragma unroll
        for (int s = 0; s < 4; ++s) {
            f32x4 sv = __builtin_amdgcn_mfma_f32_16x16x16bf16_1k(kf, qf[s], zero4, 0, 0, 0);
            float e0 = __expf(sv[0]), e1 = __expf(sv[1]);
            float e2 = __expf(sv[2]), e3 = __expf(sv[3]);
            lsum[s] += (e0 + e1) + (e2 + e3);
            uint2 pu; pu.x = pack2(e0, e1); pu.y = pack2(e2, e3);
            bf16x4 pf = __builtin_bit_cast(bf16x4, pu);
            oacc[s] = __builtin_amdgcn_mfma_f32_16x16x16bf16_1k(vf, pf, oacc[s], 0, 0, 0);
        }
    }

    // ---- normalize (tot for q=l16 matches O^T col) and write ----
    #pragma unroll
    for (int s = 0; s < 4; ++s) {
        float tot = lsum[s];
        tot += __shfl_xor(tot, 16);
        tot += __shfl_xor(tot, 32);
        const float inv = 1.f / tot;
        const int q = qb + wave * 64 + s * 16 + l16;
        uint2 w2;
        w2.x = pack2(oacc[s][0] * inv, oacc[s][1] * inv);
        w2.y = pack2(oacc[s][2] * inv, oacc[s][3] * inv);
        *(uint2*)&ctx[((size_t)(b * LSEQ + q)) * EE + hoff + quad * 4] = w2;
    }
}

// ---------------------------------------------------------------------------
// Fused GEMM + residual + LayerNorm (N = 128 only).
// seq = LN(seq + A@W^T + bias) * gamma + beta;  writes seq fp32 + bf16 mirror.
// Block = 64 rows, 256 thr = 4 waves; wave owns 16 rows x 128 cols (8 acc).
// LN row-reduce: lane holds rows quad*4+r, cols l16+16nt -> sum over nt then
// shfl_xor(1,2,4,8) across the l16 group = full 128-col reduction.
// ---------------------------------------------------------------------------
__global__ __launch_bounds__(256) void gemm_ln(
    const ushort_t* __restrict__ A, const ushort_t* __restrict__ W,
    const float* __restrict__ bias,
    const float* __restrict__ gamma, const float* __restrict__ beta,
    float* __restrict__ seq, ushort_t* __restrict__ seq_bf, int K)
{
    __shared__ ushort_t As[64 * 136];
    __shared__ ushort_t Ws[128 * 136];
    const int t = threadIdx.x;
    const int wave = t >> 6, lane = t & 63;
    const int quad = lane >> 4, l16 = lane & 15;
    const int m0 = blockIdx.x * 64;
    const int kp = K + 8;
    const int ak8 = K >> 3;

    for (int c = t; c < 64 * ak8; c += 256) {
        int row = c / ak8, col = c - row * ak8;
        *(bf16x8*)&As[row * kp + col * 8] =
            *(const bf16x8*)&A[(size_t)(m0 + row) * K + col * 8];
    }
    for (int c = t; c < 128 * ak8; c += 256) {
        int row = c / ak8, col = c - row * ak8;
        *(bf16x8*)&Ws[row * kp + col * 8] =
            *(const bf16x8*)&W[(size_t)row * K + col * 8];
    }
    __syncthreads();

    f32x4 acc[8];
    #pragma unroll
    for (int nt = 0; nt < 8; ++nt) acc[nt] = (f32x4){0.f, 0.f, 0.f, 0.f};

    const ushort_t* arow = &As[(wave * 16 + l16) * kp + quad * 8];
    const ushort_t* wrow = &Ws[l16 * kp + quad * 8];

    for (int k0 = 0; k0 < K; k0 += 32) {
        bf16x8 a = *(const bf16x8*)(arow + k0);
        #pragma unroll
        for (int nt = 0; nt < 8; ++nt) {
            bf16x8 bfr = *(const bf16x8*)(wrow + nt * 16 * kp + k0);
            acc[nt] = __builtin_amdgcn_mfma_f32_16x16x32_bf16(a, bfr, acc[nt], 0, 0, 0);
        }
    }

    // ---- epilogue: residual add, LN over 128 cols ----
    const int gr = m0 + wave * 16 + quad * 4;   // + r = global row
    float v[8][4];
    #pragma unroll
    for (int nt = 0; nt < 8; ++nt) {
        const int n = nt * 16 + l16;
        const float bs = bias[n];
        #pragma unroll
        for (int r = 0; r < 4; ++r)
            v[nt][r] = acc[nt][r] + bs + seq[(size_t)(gr + r) * EE + n];
    }
    float mean[4], rstd[4];
    #pragma unroll
    for (int r = 0; r < 4; ++r) {
        float s = 0.f;
        #pragma unroll
        for (int nt = 0; nt < 8; ++nt) s += v[nt][r];
        s += __shfl_xor(s, 1); s += __shfl_xor(s, 2);
        s += __shfl_xor(s, 4); s += __shfl_xor(s, 8);
        mean[r] = s * (1.f / 128.f);
    }
    #pragma unroll
    for (int r = 0; r < 4; ++r) {
        float s2 = 0.f;
        #pragma unroll
        for (int nt = 0; nt < 8; ++nt) {
            float d = v[nt][r] - mean[r];
            s2 += d * d;
        }
        s2 += __shfl_xor(s2, 1); s2 += __shfl_xor(s2, 2);
        s2 += __shfl_xor(s2, 4); s2 += __shfl_xor(s2, 8);
        rstd[r] = 1.f / sqrtf(s2 * (1.f / 128.f) + 1e-5f);
    }
    #pragma unroll
    for (int nt = 0; nt < 8; ++nt) {
        const int n = nt * 16 + l16;
        const float g = gamma[n], be = beta[n];
        #pragma unroll
        for (int r = 0; r < 4; ++r) {
            float y = (v[nt][r] - mean[r]) * rstd[r] * g + be;
            seq[(size_t)(gr + r) * EE + n] = y;
            seq_bf[(size_t)(gr + r) * EE + n] = f2b(y);
        }
    }
}

// ---------------------------------------------------------------------------
// Final projection, split-K MFMA. out[b,o] = seq_flat[b,:]·out_w[o,:]+out_b[o]
// ---------------------------------------------------------------------------
#define PKC 192
#define PNBLK (KOUT / PKC)   // 512
__global__ __launch_bounds__(256) void out_gemm3(
    const ushort_t* __restrict__ seqbf, const float* __restrict__ out_w,
    float* __restrict__ part)
{
    const int t = threadIdx.x;
    const int wave = t >> 6, lane = t & 63;
    const int quad = lane >> 4, l16 = lane & 15;
    const size_t k0 = (size_t)blockIdx.x * PKC;
    const int n0 = wave * 32;

    f32x4 acc[2][2];
    #pragma unroll
    for (int mt = 0; mt < 2; ++mt)
        #pragma unroll
        for (int nt = 0; nt < 2; ++nt)
            acc[mt][nt] = (f32x4){0.f, 0.f, 0.f, 0.f};

    const ushort_t* a0p = seqbf + (size_t)l16 * KOUT + k0 + quad * 8;
    const ushort_t* a1p = a0p + (size_t)16 * KOUT;
    const float* w0p = out_w + (size_t)(n0 + l16) * KOUT + k0 + quad * 8;
    const float* w1p = w0p + (size_t)16 * KOUT;

    #pragma unroll
    for (int ks = 0; ks < PKC; ks += 32) {
        bf16x8 a0 = *(const bf16x8*)(a0p + ks);
        bf16x8 a1 = *(const bf16x8*)(a1p + ks);
        float4 wa0 = *(const float4*)(w0p + ks);
        float4 wa1 = *(const float4*)(w0p + ks + 4);
        float4 wb0 = *(const float4*)(w1p + ks);
        float4 wb1 = *(const float4*)(w1p + ks + 4);
        bf16x8 bf0, bf1;
        bf0[0] = (short)f2b(wa0.x); bf0[1] = (short)f2b(wa0.y);
        bf0[2] = (short)f2b(wa0.z); bf0[3] = (short)f2b(wa0.w);
        bf0[4] = (short)f2b(wa1.x); bf0[5] = (short)f2b(wa1.y);
        bf0[6] = (short)f2b(wa1.z); bf0[7] = (short)f2b(wa1.w);
        bf1[0] = (short)f2b(wb0.x); bf1[1] = (short)f2b(wb0.y);
        bf1[2] = (short)f2b(wb0.z); bf1[3] = (short)f2b(wb0.w);
        bf1[4] = (short)f2b(wb1.x); bf1[5] = (short)f2b(wb1.y);
        bf1[6] = (short)f2b(wb1.z); bf1[7] = (short)f2b(wb1.w);
        acc[0][0] = __builtin_amdgcn_mfma_f32_16x16x32_bf16(a0, bf0, acc[0][0], 0, 0, 0);
        acc[1][0] = __builtin_amdgcn_mfma_f32_16x16x32_bf16(a1, bf0, acc[1][0], 0, 0, 0);
        acc[0][1] = __builtin_amdgcn_mfma_f32_16x16x32_bf16(a0, bf1, acc[0][1], 0, 0, 0);
        acc[1][1] = __builtin_amdgcn_mfma_f32_16x16x32_bf16(a1, bf1, acc[1][1], 0, 0, 0);
    }

    float* pb = part + (size_t)blockIdx.x * (32 * 128);
    #pragma unroll
    for (int mt = 0; mt < 2; ++mt)
        #pragma unroll
        for (int nt = 0; nt < 2; ++nt)
            #pragma unroll
            for (int r = 0; r < 4; ++r)
                pb[(mt * 16 + quad * 4 + r) * 128 + n0 + nt * 16 + l16] = acc[mt][nt][r];
}

// out[i=b*128+n] = out_b[n] + sum_blk part[blk][b][n]
__global__ __launch_bounds__(256) void out_reduce(
    const float* __restrict__ part, const float* __restrict__ out_b,
    float* __restrict__ out)
{
    const int i = blockIdx.x * 256 + threadIdx.x;   // 0..4095
    const float* p = part + i;
    float s0 = 0.f, s1 = 0.f, s2 = 0.f, s3 = 0.f;
    for (int blk = 0; blk < PNBLK; blk += 4) {
        s0 += p[(size_t)blk * 4096];
        s1 += p[(size_t)(blk + 1) * 4096];
        s2 += p[(size_t)(blk + 2) * 4096];
        s3 += p[(size_t)(blk + 3) * 4096];
    }
    out[i] = out_b[i & (OUTN - 1)] + ((s0 + s1) + (s2 + s3));
}

// ---------------------------------------------------------------------------
extern "C" void kernel_launch(void* const* d_in, const int* in_sizes, int n_in,
                              void* d_out, int out_size, void* d_ws, size_t ws_size,
                              hipStream_t stream)
{
    const float* x          = (const float*)d_in[0];
    const float* prototypes = (const float*)d_in[1];
    const float* emb_w      = (const float*)d_in[2];
    const float* emb_b      = (const float*)d_in[3];
    const float* proj_w     = (const float*)d_in[4];
    const float* proj_b     = (const float*)d_in[5];
    const float* in_proj_w  = (const float*)d_in[6];
    const float* in_proj_b  = (const float*)d_in[7];
    const float* out_proj_w = (const float*)d_in[8];
    const float* out_proj_b = (const float*)d_in[9];
    const float* ln1_s      = (const float*)d_in[10];
    const float* ln1_b      = (const float*)d_in[11];
    const float* ffn_w1     = (const float*)d_in[12];
    const float* ffn_b1     = (const float*)d_in[13];
    const float* ffn_w2     = (const float*)d_in[14];
    const float* ffn_b2     = (const float*)d_in[15];
    const float* ln2_s      = (const float*)d_in[16];
    const float* ln2_b      = (const float*)d_in[17];
    const float* out_w      = (const float*)d_in[18];
    const float* out_b      = (const float*)d_in[19];
    float* out = (float*)d_out;
    char* base = (char*)d_ws;

    // workspace layout (bytes)
    float*    seq    = (float*)base;                        // 12,582,912
    float*    tmp    = (float*)(base + 12582912);           // 12,582,912 (= part)
    ushort_t* seq_bf = (ushort_t*)(base + 25165824);        //  6,291,456
    ushort_t* qkv_bf = (ushort_t*)(base + 31457280);        // 18,874,368
    ushort_t* ctx_bf = (ushort_t*)(base + 50331648);        //  6,291,456
    ushort_t* h_bf   = (ushort_t*)(base + 56623104);        //  3,145,728
    ushort_t* w_bf   = (ushort_t*)(base + 59768832);        //    655,360 B region
    float*    part   = tmp;
    (void)ws_size;

    ushort_t* w_in  = w_bf;            // [2][384][128]
    ushort_t* w_out = w_bf + 98304;    // [2][128][128]
    ushort_t* w_f1  = w_bf + 131072;   // [2][64][128]
    ushort_t* w_f2  = w_bf + 147456;   // [2][128][64]

    cast_all_kernel<<<(163840 + 255) / 256, 256, 0, stream>>>(
        in_proj_w, 98304, out_proj_w, 32768, ffn_w1, 16384, ffn_w2, 16384,
        w_in, w_out, w_f1, w_f2);

    embed_kernel<<<ROWS, 128, 0, stream>>>(x, prototypes, emb_w, emb_b,
                                           proj_w, proj_b, seq, seq_bf);

    for (int l = 0; l < 2; ++l) {
        // qkv = seq @ Wqkv^T + b -> bf16 [24576, 384], Q cols pre-scaled 0.25
        gemm_mfma<<<dim3(6, 192), 256, 0, stream>>>(
            seq_bf, w_in + (size_t)l * 49152, in_proj_b + l * 384,
            qkv_bf, ROWS, 384, 128, 2 | 4);
        attention_mfma<<<dim3(BB * HH, 3), 256, 0, stream>>>(qkv_bf, ctx_bf);
        // seq = LN(seq + ctx @ Wout^T + b)   (fused)
        gemm_ln<<<ROWS / 64, 256, 0, stream>>>(
            ctx_bf, w_out + (size_t)l * 16384, out_proj_b + l * 128,
            ln1_s + l * EE, ln1_b + l * EE, seq, seq_bf, 128);
        // h = elu(seq @ W1^T + b1) -> bf16 [24576, 64]
        gemm_mfma<<<dim3(1, 192), 256, 0, stream>>>(
            seq_bf, w_f1 + (size_t)l * 8192, ffn_b1 + l * II,
            h_bf, ROWS, 64, 128, 1 | 2);
        // seq = LN(seq + h @ W2^T + b2)   (fused)
        gemm_ln<<<ROWS / 64, 256, 0, stream>>>(
            h_bf, w_f2 + (size_t)l * 8192, ffn_b2 + l * EE,
            ln2_s + l * EE, ln2_b + l * EE, seq, seq_bf, 64);
    }

    out_gemm3<<<PNBLK, 256, 0, stream>>>(seq_bf, out_w, part);
    out_reduce<<<BB * OUTN / 256, 256, 0, stream>>>(part, out_b, out);
}

// Round 7
// 372.094 us; speedup vs baseline: 2.4362x; 1.0825x over previous
//
#include <hip/hip_runtime.h>
#include <hip/hip_bf16.h>
#include <math.h>

typedef unsigned short ushort_t;
typedef unsigned int uint_t;

// Problem constants
#define BB 32
#define PP 6
#define DD 96
#define EE 128
#define HH 8
#define II 64
#define KK 32
#define LSEQ 768            // N*D
#define ROWS (BB * LSEQ)    // 24576 token rows
#define OUTN 128
#define KOUT (LSEQ * EE)    // 98304

using bf16x8 = __attribute__((ext_vector_type(8))) short;
using bf16x4 = __attribute__((ext_vector_type(4))) short;
using f32x4  = __attribute__((ext_vector_type(4))) float;
using u32x4  = __attribute__((ext_vector_type(4))) uint_t;

__device__ __forceinline__ ushort_t f2b(float f) {
    __hip_bfloat16 h = __float2bfloat16(f);
    return *reinterpret_cast<ushort_t*>(&h);
}
// pack two fp32 -> (bf16(hi)<<16)|bf16(lo) by TRUNCATION: one v_perm_b32.
__device__ __forceinline__ uint_t permpack(float hi, float lo) {
    return __builtin_amdgcn_perm(__builtin_bit_cast(uint_t, hi),
                                 __builtin_bit_cast(uint_t, lo), 0x07060302u);
}

// ---------------------------------------------------------------------------
// Cast fp32 -> bf16, all four weight tensors in one launch.
// ---------------------------------------------------------------------------
__global__ void cast_all_kernel(
    const float* __restrict__ s0, int n0, const float* __restrict__ s1, int n1,
    const float* __restrict__ s2, int n2, const float* __restrict__ s3, int n3,
    ushort_t* __restrict__ d0, ushort_t* __restrict__ d1,
    ushort_t* __restrict__ d2, ushort_t* __restrict__ d3)
{
    int i = blockIdx.x * 256 + threadIdx.x;
    if (i < n0) { d0[i] = f2b(s0[i]); return; }
    i -= n0;
    if (i < n1) { d1[i] = f2b(s1[i]); return; }
    i -= n1;
    if (i < n2) { d2[i] = f2b(s2[i]); return; }
    i -= n2;
    if (i < n3) { d3[i] = f2b(s3[i]); }
}

// ---------------------------------------------------------------------------
// Embed: row-normalize x, cosine-argmax prototype per (row,d), project both
// through emb_w/proj_w, add positional encoding. One block per row.
// ---------------------------------------------------------------------------
__global__ __launch_bounds__(128) void embed_kernel(
    const float* __restrict__ x, const float* __restrict__ prot,
    const float* __restrict__ emb_w, const float* __restrict__ emb_b,
    const float* __restrict__ proj_w, const float* __restrict__ proj_b,
    float* __restrict__ seq, ushort_t* __restrict__ seq_bf)
{
    const int r = blockIdx.x;      // 0..24575  (= b*L + l)
    const int t = threadIdx.x;     // 0..127
    __shared__ float xrow[PP];
    __shared__ float sel[PP];

    if (t < PP) xrow[t] = x[r * PP + t];
    __syncthreads();

    float nx = 0.f;
    #pragma unroll
    for (int p = 0; p < PP; ++p) nx += xrow[p] * xrow[p];
    const float xinv = 1.f / fmaxf(sqrtf(nx), 1e-12f);

    const int d = r % DD;
    if (t < KK) {
        const float* pr = prot + (d * KK + t) * PP;
        float pp[PP];
        float np2 = 0.f;
        #pragma unroll
        for (int p = 0; p < PP; ++p) { pp[p] = pr[p]; np2 += pp[p] * pp[p]; }
        const float pinv = 1.f / fmaxf(sqrtf(np2), 1e-12f);
        float dot = 0.f;
        #pragma unroll
        for (int p = 0; p < PP; ++p) dot += xrow[p] * pp[p];
        float sim = dot * xinv * pinv;
        int k = t;
        #pragma unroll
        for (int off = 16; off; off >>= 1) {
            float osim = __shfl_down(sim, off);
            int   ok   = __shfl_down(k, off);
            if (osim > sim || (osim == sim && ok < k)) { sim = osim; k = ok; }
        }
        k = __shfl(k, 0);
        if (t == k) {
            #pragma unroll
            for (int p = 0; p < PP; ++p) sel[p] = pp[p] * pinv;
        }
    }
    __syncthreads();

    float acc = emb_b[t] + proj_b[t];
    #pragma unroll
    for (int p = 0; p < PP; ++p) acc = fmaf(xrow[p], emb_w[t * PP + p], acc);
    #pragma unroll
    for (int p = 0; p < PP; ++p) acc = fmaf(sel[p], proj_w[t * PP + p], acc);

    const int lpos = r % LSEQ;
    const float twoj = (float)((t >> 1) * 2);
    const float div = __expf(twoj * (-9.210340371976184f / 128.0f));
    const float ang = (float)lpos * div;
    const float pe = (t & 1) ? cosf(ang) : sinf(ang);
    const float v = acc + pe;
    seq[(size_t)r * EE + t] = v;
    seq_bf[(size_t)r * EE + t] = f2b(v);
}

// ---------------------------------------------------------------------------
// MFMA bf16 GEMM: C[M,N] = A[M,K](bf16) @ W[N,K](bf16)^T + bias(f32)
// Block tile 128(M) x 64(N), 256 thr = 4 waves.
// flags: 1 = ELU; 2 = output bf16; 4 = scale cols n<128 by 0.25 (Q pre-scale)
// ---------------------------------------------------------------------------
__global__ __launch_bounds__(256) void gemm_mfma(
    const ushort_t* __restrict__ A, const ushort_t* __restrict__ W,
    const float* __restrict__ bias, void* __restrict__ Cout,
    int M, int N, int K, int flags)
{
    __shared__ ushort_t As[128 * 136];   // row stride kp = K+8
    __shared__ ushort_t Ws[64 * 136];
    const int t = threadIdx.x;
    const int wave = t >> 6, lane = t & 63;
    const int quad = lane >> 4, l16 = lane & 15;
    const int m0 = blockIdx.y * 128, n0 = blockIdx.x * 64;
    const int kp = K + 8;
    const int ak8 = K >> 3;  // 16B chunks per row

    for (int c = t; c < 128 * ak8; c += 256) {
        int row = c / ak8, col = c - row * ak8;
        *(bf16x8*)&As[row * kp + col * 8] =
            *(const bf16x8*)&A[(size_t)(m0 + row) * K + col * 8];
    }
    for (int c = t; c < 64 * ak8; c += 256) {
        int row = c / ak8, col = c - row * ak8;
        *(bf16x8*)&Ws[row * kp + col * 8] =
            *(const bf16x8*)&W[(size_t)(n0 + row) * K + col * 8];
    }
    __syncthreads();

    f32x4 acc[2][4];
    #pragma unroll
    for (int mt = 0; mt < 2; ++mt)
        #pragma unroll
        for (int nt = 0; nt < 4; ++nt)
            acc[mt][nt] = (f32x4){0.f, 0.f, 0.f, 0.f};

    const ushort_t* arow0 = &As[(wave * 32 + l16) * kp + quad * 8];
    const ushort_t* arow1 = arow0 + 16 * kp;
    const ushort_t* wrow  = &Ws[l16 * kp + quad * 8];

    for (int k0 = 0; k0 < K; k0 += 32) {
        bf16x8 a0 = *(const bf16x8*)(arow0 + k0);
        bf16x8 a1 = *(const bf16x8*)(arow1 + k0);
        #pragma unroll
        for (int nt = 0; nt < 4; ++nt) {
            bf16x8 b = *(const bf16x8*)(wrow + nt * 16 * kp + k0);
            acc[0][nt] = __builtin_amdgcn_mfma_f32_16x16x32_bf16(a0, b, acc[0][nt], 0, 0, 0);
            acc[1][nt] = __builtin_amdgcn_mfma_f32_16x16x32_bf16(a1, b, acc[1][nt], 0, 0, 0);
        }
    }

    #pragma unroll
    for (int mt = 0; mt < 2; ++mt) {
        #pragma unroll
        for (int nt = 0; nt < 4; ++nt) {
            const int n = n0 + nt * 16 + l16;
            const float bs = bias[n];
            #pragma unroll
            for (int r = 0; r < 4; ++r) {
                const int m = m0 + wave * 32 + mt * 16 + quad * 4 + r;
                float v = acc[mt][nt][r] + bs;
                if (flags & 1) v = v > 0.f ? v : expm1f(v);
                if ((flags & 4) && n < EE) v *= 0.25f;   // Q pre-scale
                if (flags & 2) ((ushort_t*)Cout)[(size_t)m * N + n] = f2b(v);
                else           ((float*)Cout)[(size_t)m * N + n] = v;
            }
        }
    }
}

// ---------------------------------------------------------------------------
// MFMA flash attention v4 — 16x16x16 mfma, zero cross-lane movement,
// 512 threads (8 waves -> 24 waves/CU at 3 blocks/CU), v_perm trunc packing.
// Block = (bh, qchunk of 256 rows); wave owns 32 q rows = 2 strips of 16.
//   S^T:  mfma_16x16x16(K-frag, Q-frag). K read straight from global
//         (8B/lane, L2-hot). C: lane = S^T[key=quad*4+r][q=l16].
//   exp:  in-register; the exp'd C-regs ARE the PV B-frag.
//   PV:   mfma_16x16x16(V^T-frag from LDS, P-frag) -> O^T[dim][q].
//   norm: lsum xor16+xor32; uint2 store via v_perm.
// LDS: Vt only, 25.3 KB. Q pre-scaled by 0.25 (gemm_mfma flag 4).
// ---------------------------------------------------------------------------
#define VTS 792   // Vt row stride (ushorts)
__global__ __launch_bounds__(512) void attention_mfma(
    const ushort_t* __restrict__ qkv, ushort_t* __restrict__ ctx)
{
    __shared__ ushort_t Vt[16 * VTS];

    const int bh = blockIdx.x;
    const int b = bh >> 3, h = bh & 7;
    const int qb = blockIdx.y * 256;
    const int t = threadIdx.x;
    const int wave = t >> 6, lane = t & 63;
    const int quad = lane >> 4, l16 = lane & 15;
    const size_t bbase = (size_t)b * LSEQ * 384;
    const int hoff = h * 16;

    // ---- stage V transposed ----
    for (int idx = t; idx < 1536; idx += 512) {
        int row = idx >> 1, half = idx & 1;
        bf16x8 v = *(const bf16x8*)&qkv[bbase + (size_t)row * 384 + 2 * EE + hoff + half * 8];
        #pragma unroll
        for (int j = 0; j < 8; ++j)
            Vt[(half * 8 + j) * VTS + row] = (ushort_t)v[j];
    }

    // ---- Q fragments: B[k=dim quad*4+j][n=q l16] = Q[q][dim] ----
    bf16x4 qf[2];
    #pragma unroll
    for (int s = 0; s < 2; ++s) {
        int row = qb + wave * 32 + s * 16 + l16;
        qf[s] = *(const bf16x4*)&qkv[bbase + (size_t)row * 384 + hoff + quad * 4];
    }
    __syncthreads();

    f32x4 oacc[2];
    oacc[0] = (f32x4){0.f, 0.f, 0.f, 0.f};
    oacc[1] = (f32x4){0.f, 0.f, 0.f, 0.f};
    float lsum[2] = {0.f, 0.f};
    const f32x4 zero4 = (f32x4){0.f, 0.f, 0.f, 0.f};

    const ushort_t* kbase = qkv + bbase + EE + hoff + quad * 4;

    for (int ch = 0; ch < LSEQ; ch += 16) {
        // K A-frag: K[key=ch+l16][dim=quad*4..+3]  (global, 8B/lane)
        bf16x4 kf = *(const bf16x4*)&kbase[(size_t)(ch + l16) * 384];
        // V^T A-frag: V^T[dim=l16][keys ch+quad*4..+3]  (LDS b64)
        bf16x4 vf = *(const bf16x4*)&Vt[l16 * VTS + ch + quad * 4];

        #pragma unroll
        for (int s = 0; s < 2; ++s) {
            f32x4 sv = __builtin_amdgcn_mfma_f32_16x16x16bf16_1k(kf, qf[s], zero4, 0, 0, 0);
            float e0 = __expf(sv[0]), e1 = __expf(sv[1]);
            float e2 = __expf(sv[2]), e3 = __expf(sv[3]);
            lsum[s] += (e0 + e1) + (e2 + e3);
            uint2 pu;
            pu.x = permpack(e1, e0);          // trunc pack: 1 v_perm for 2 vals
            pu.y = permpack(e3, e2);
            bf16x4 pf = __builtin_bit_cast(bf16x4, pu);
            oacc[s] = __builtin_amdgcn_mfma_f32_16x16x16bf16_1k(vf, pf, oacc[s], 0, 0, 0);
        }
    }

    // ---- normalize (tot for q=l16 matches O^T col) and write ----
    #pragma unroll
    for (int s = 0; s < 2; ++s) {
        float tot = lsum[s];
        tot += __shfl_xor(tot, 16);
        tot += __shfl_xor(tot, 32);
        const float inv = 1.f / tot;
        const int q = qb + wave * 32 + s * 16 + l16;
        uint2 w2;
        w2.x = permpack(oacc[s][1] * inv, oacc[s][0] * inv);
        w2.y = permpack(oacc[s][3] * inv, oacc[s][2] * inv);
        *(uint2*)&ctx[((size_t)(b * LSEQ + q)) * EE + hoff + quad * 4] = w2;
    }
}

// ---------------------------------------------------------------------------
// Fused GEMM + residual + LayerNorm (N = 128 only).
// seq = LN(seq + A@W^T + bias) * gamma + beta;  writes seq fp32 + bf16 mirror.
// Block = 64 rows, 256 thr = 4 waves; wave owns 16 rows x 128 cols (8 acc).
// ---------------------------------------------------------------------------
__global__ __launch_bounds__(256) void gemm_ln(
    const ushort_t* __restrict__ A, const ushort_t* __restrict__ W,
    const float* __restrict__ bias,
    const float* __restrict__ gamma, const float* __restrict__ beta,
    float* __restrict__ seq, ushort_t* __restrict__ seq_bf, int K)
{
    __shared__ ushort_t As[64 * 136];
    __shared__ ushort_t Ws[128 * 136];
    const int t = threadIdx.x;
    const int wave = t >> 6, lane = t & 63;
    const int quad = lane >> 4, l16 = lane & 15;
    const int m0 = blockIdx.x * 64;
    const int kp = K + 8;
    const int ak8 = K >> 3;

    for (int c = t; c < 64 * ak8; c += 256) {
        int row = c / ak8, col = c - row * ak8;
        *(bf16x8*)&As[row * kp + col * 8] =
            *(const bf16x8*)&A[(size_t)(m0 + row) * K + col * 8];
    }
    for (int c = t; c < 128 * ak8; c += 256) {
        int row = c / ak8, col = c - row * ak8;
        *(bf16x8*)&Ws[row * kp + col * 8] =
            *(const bf16x8*)&W[(size_t)row * K + col * 8];
    }
    __syncthreads();

    f32x4 acc[8];
    #pragma unroll
    for (int nt = 0; nt < 8; ++nt) acc[nt] = (f32x4){0.f, 0.f, 0.f, 0.f};

    const ushort_t* arow = &As[(wave * 16 + l16) * kp + quad * 8];
    const ushort_t* wrow = &Ws[l16 * kp + quad * 8];

    for (int k0 = 0; k0 < K; k0 += 32) {
        bf16x8 a = *(const bf16x8*)(arow + k0);
        #pragma unroll
        for (int nt = 0; nt < 8; ++nt) {
            bf16x8 bfr = *(const bf16x8*)(wrow + nt * 16 * kp + k0);
            acc[nt] = __builtin_amdgcn_mfma_f32_16x16x32_bf16(a, bfr, acc[nt], 0, 0, 0);
        }
    }

    // ---- epilogue: residual add, LN over 128 cols ----
    const int gr = m0 + wave * 16 + quad * 4;   // + r = global row
    float v[8][4];
    #pragma unroll
    for (int nt = 0; nt < 8; ++nt) {
        const int n = nt * 16 + l16;
        const float bs = bias[n];
        #pragma unroll
        for (int r = 0; r < 4; ++r)
            v[nt][r] = acc[nt][r] + bs + seq[(size_t)(gr + r) * EE + n];
    }
    float mean[4], rstd[4];
    #pragma unroll
    for (int r = 0; r < 4; ++r) {
        float s = 0.f;
        #pragma unroll
        for (int nt = 0; nt < 8; ++nt) s += v[nt][r];
        s += __shfl_xor(s, 1); s += __shfl_xor(s, 2);
        s += __shfl_xor(s, 4); s += __shfl_xor(s, 8);
        mean[r] = s * (1.f / 128.f);
    }
    #pragma unroll
    for (int r = 0; r < 4; ++r) {
        float s2 = 0.f;
        #pragma unroll
        for (int nt = 0; nt < 8; ++nt) {
            float d = v[nt][r] - mean[r];
            s2 += d * d;
        }
        s2 += __shfl_xor(s2, 1); s2 += __shfl_xor(s2, 2);
        s2 += __shfl_xor(s2, 4); s2 += __shfl_xor(s2, 8);
        rstd[r] = 1.f / sqrtf(s2 * (1.f / 128.f) + 1e-5f);
    }
    #pragma unroll
    for (int nt = 0; nt < 8; ++nt) {
        const int n = nt * 16 + l16;
        const float g = gamma[n], be = beta[n];
        #pragma unroll
        for (int r = 0; r < 4; ++r) {
            float y = (v[nt][r] - mean[r]) * rstd[r] * g + be;
            seq[(size_t)(gr + r) * EE + n] = y;
            seq_bf[(size_t)(gr + r) * EE + n] = f2b(y);
        }
    }
}

// ---------------------------------------------------------------------------
// Final projection, split-K MFMA. out[b,o] = seq_flat[b,:]·out_w[o,:]+out_b[o]
// W converted fp32->bf16 in-register via v_perm truncation (8 perms/iter).
// ---------------------------------------------------------------------------
#define PKC 192
#define PNBLK (KOUT / PKC)   // 512
__global__ __launch_bounds__(256) void out_gemm3(
    const ushort_t* __restrict__ seqbf, const float* __restrict__ out_w,
    float* __restrict__ part)
{
    const int t = threadIdx.x;
    const int wave = t >> 6, lane = t & 63;
    const int quad = lane >> 4, l16 = lane & 15;
    const size_t k0 = (size_t)blockIdx.x * PKC;
    const int n0 = wave * 32;

    f32x4 acc[2][2];
    #pragma unroll
    for (int mt = 0; mt < 2; ++mt)
        #pragma unroll
        for (int nt = 0; nt < 2; ++nt)
            acc[mt][nt] = (f32x4){0.f, 0.f, 0.f, 0.f};

    const ushort_t* a0p = seqbf + (size_t)l16 * KOUT + k0 + quad * 8;
    const ushort_t* a1p = a0p + (size_t)16 * KOUT;
    const float* w0p = out_w + (size_t)(n0 + l16) * KOUT + k0 + quad * 8;
    const float* w1p = w0p + (size_t)16 * KOUT;

    #pragma unroll
    for (int ks = 0; ks < PKC; ks += 32) {
        bf16x8 a0 = *(const bf16x8*)(a0p + ks);
        bf16x8 a1 = *(const bf16x8*)(a1p + ks);
        float4 wa0 = *(const float4*)(w0p + ks);
        float4 wa1 = *(const float4*)(w0p + ks + 4);
        float4 wb0 = *(const float4*)(w1p + ks);
        float4 wb1 = *(const float4*)(w1p + ks + 4);
        u32x4 b0, b1;
        b0[0] = permpack(wa0.y, wa0.x); b0[1] = permpack(wa0.w, wa0.z);
        b0[2] = permpack(wa1.y, wa1.x); b0[3] = permpack(wa1.w, wa1.z);
        b1[0] = permpack(wb0.y, wb0.x); b1[1] = permpack(wb0.w, wb0.z);
        b1[2] = permpack(wb1.y, wb1.x); b1[3] = permpack(wb1.w, wb1.z);
        bf16x8 bf0 = __builtin_bit_cast(bf16x8, b0);
        bf16x8 bf1 = __builtin_bit_cast(bf16x8, b1);
        acc[0][0] = __builtin_amdgcn_mfma_f32_16x16x32_bf16(a0, bf0, acc[0][0], 0, 0, 0);
        acc[1][0] = __builtin_amdgcn_mfma_f32_16x16x32_bf16(a1, bf0, acc[1][0], 0, 0, 0);
        acc[0][1] = __builtin_amdgcn_mfma_f32_16x16x32_bf16(a0, bf1, acc[0][1], 0, 0, 0);
        acc[1][1] = __builtin_amdgcn_mfma_f32_16x16x32_bf16(a1, bf1, acc[1][1], 0, 0, 0);
    }

    float* pb = part + (size_t)blockIdx.x * (32 * 128);
    #pragma unroll
    for (int mt = 0; mt < 2; ++mt)
        #pragma unroll
        for (int nt = 0; nt < 2; ++nt)
            #pragma unroll
            for (int r = 0; r < 4; ++r)
                pb[(mt * 16 + quad * 4 + r) * 128 + n0 + nt * 16 + l16] = acc[mt][nt][r];
}

// out[i=b*128+n] = out_b[n] + sum_blk part[blk][b][n]
__global__ __launch_bounds__(256) void out_reduce(
    const float* __restrict__ part, const float* __restrict__ out_b,
    float* __restrict__ out)
{
    const int i = blockIdx.x * 256 + threadIdx.x;   // 0..4095
    const float* p = part + i;
    float s0 = 0.f, s1 = 0.f, s2 = 0.f, s3 = 0.f;
    for (int blk = 0; blk < PNBLK; blk += 4) {
        s0 += p[(size_t)blk * 4096];
        s1 += p[(size_t)(blk + 1) * 4096];
        s2 += p[(size_t)(blk + 2) * 4096];
        s3 += p[(size_t)(blk + 3) * 4096];
    }
    out[i] = out_b[i & (OUTN - 1)] + ((s0 + s1) + (s2 + s3));
}

// ---------------------------------------------------------------------------
extern "C" void kernel_launch(void* const* d_in, const int* in_sizes, int n_in,
                              void* d_out, int out_size, void* d_ws, size_t ws_size,
                              hipStream_t stream)
{
    const float* x          = (const float*)d_in[0];
    const float* prototypes = (const float*)d_in[1];
    const float* emb_w      = (const float*)d_in[2];
    const float* emb_b      = (const float*)d_in[3];
    const float* proj_w     = (const float*)d_in[4];
    const float* proj_b     = (const float*)d_in[5];
    const float* in_proj_w  = (const float*)d_in[6];
    const float* in_proj_b  = (const float*)d_in[7];
    const float* out_proj_w = (const float*)d_in[8];
    const float* out_proj_b = (const float*)d_in[9];
    const float* ln1_s      = (const float*)d_in[10];
    const float* ln1_b      = (const float*)d_in[11];
    const float* ffn_w1     = (const float*)d_in[12];
    const float* ffn_b1     = (const float*)d_in[13];
    const float* ffn_w2     = (const float*)d_in[14];
    const float* ffn_b2     = (const float*)d_in[15];
    const float* ln2_s      = (const float*)d_in[16];
    const float* ln2_b      = (const float*)d_in[17];
    const float* out_w      = (const float*)d_in[18];
    const float* out_b      = (const float*)d_in[19];
    float* out = (float*)d_out;
    char* base = (char*)d_ws;

    // workspace layout (bytes)
    float*    seq    = (float*)base;                        // 12,582,912
    float*    tmp    = (float*)(base + 12582912);           // 12,582,912 (= part)
    ushort_t* seq_bf = (ushort_t*)(base + 25165824);        //  6,291,456
    ushort_t* qkv_bf = (ushort_t*)(base + 31457280);        // 18,874,368
    ushort_t* ctx_bf = (ushort_t*)(base + 50331648);        //  6,291,456
    ushort_t* h_bf   = (ushort_t*)(base + 56623104);        //  3,145,728
    ushort_t* w_bf   = (ushort_t*)(base + 59768832);        //    655,360 B region
    float*    part   = tmp;
    (void)ws_size;

    ushort_t* w_in  = w_bf;            // [2][384][128]
    ushort_t* w_out = w_bf + 98304;    // [2][128][128]
    ushort_t* w_f1  = w_bf + 131072;   // [2][64][128]
    ushort_t* w_f2  = w_bf + 147456;   // [2][128][64]

    cast_all_kernel<<<(163840 + 255) / 256, 256, 0, stream>>>(
        in_proj_w, 98304, out_proj_w, 32768, ffn_w1, 16384, ffn_w2, 16384,
        w_in, w_out, w_f1, w_f2);

    embed_kernel<<<ROWS, 128, 0, stream>>>(x, prototypes, emb_w, emb_b,
                                           proj_w, proj_b, seq, seq_bf);

    for (int l = 0; l < 2; ++l) {
        // qkv = seq @ Wqkv^T + b -> bf16 [24576, 384], Q cols pre-scaled 0.25
        gemm_mfma<<<dim3(6, 192), 256, 0, stream>>>(
            seq_bf, w_in + (size_t)l * 49152, in_proj_b + l * 384,
            qkv_bf, ROWS, 384, 128, 2 | 4);
        attention_mfma<<<dim3(BB * HH, 3), 512, 0, stream>>>(qkv_bf, ctx_bf);
        // seq = LN(seq + ctx @ Wout^T + b)   (fused)
        gemm_ln<<<ROWS / 64, 256, 0, stream>>>(
            ctx_bf, w_out + (size_t)l * 16384, out_proj_b + l * 128,
            ln1_s + l * EE, ln1_b + l * EE, seq, seq_bf, 128);
        // h = elu(seq @ W1^T + b1) -> bf16 [24576, 64]
        gemm_mfma<<<dim3(1, 192), 256, 0, stream>>>(
            seq_bf, w_f1 + (size_t)l * 8192, ffn_b1 + l * II,
            h_bf, ROWS, 64, 128, 1 | 2);
        // seq = LN(seq + h @ W2^T + b2)   (fused)
        gemm_ln<<<ROWS / 64, 256, 0, stream>>>(
            h_bf, w_f2 + (size_t)l * 8192, ffn_b2 + l * EE,
            ln2_s + l * EE, ln2_b + l * EE, seq, seq_bf, 64);
    }

    out_gemm3<<<PNBLK, 256, 0, stream>>>(seq_bf, out_w, part);
    out_reduce<<<BB * OUTN / 256, 256, 0, stream>>>(part, out_b, out);
}

// Round 8
// 344.189 us; speedup vs baseline: 2.6337x; 1.0811x over previous
//
#include <hip/hip_runtime.h>
#include <hip/hip_bf16.h>
#include <math.h>

typedef unsigned short ushort_t;
typedef unsigned int uint_t;

// Problem constants
#define BB 32
#define PP 6
#define DD 96
#define EE 128
#define HH 8
#define II 64
#define KK 32
#define LSEQ 768            // N*D
#define ROWS (BB * LSEQ)    // 24576 token rows
#define OUTN 128
#define KOUT (LSEQ * EE)    // 98304

using bf16x8 = __attribute__((ext_vector_type(8))) short;
using bf16x4 = __attribute__((ext_vector_type(4))) short;
using f32x4  = __attribute__((ext_vector_type(4))) float;
using u32x4  = __attribute__((ext_vector_type(4))) uint_t;

__device__ __forceinline__ ushort_t f2b(float f) {
    __hip_bfloat16 h = __float2bfloat16(f);
    return *reinterpret_cast<ushort_t*>(&h);
}
// pack two fp32 -> (bf16(hi)<<16)|bf16(lo) by TRUNCATION: one v_perm_b32.
__device__ __forceinline__ uint_t permpack(float hi, float lo) {
    return __builtin_amdgcn_perm(__builtin_bit_cast(uint_t, hi),
                                 __builtin_bit_cast(uint_t, lo), 0x07060302u);
}

// ---------------------------------------------------------------------------
// Cast fp32 -> bf16, all four weight tensors in one launch.
// ---------------------------------------------------------------------------
__global__ void cast_all_kernel(
    const float* __restrict__ s0, int n0, const float* __restrict__ s1, int n1,
    const float* __restrict__ s2, int n2, const float* __restrict__ s3, int n3,
    ushort_t* __restrict__ d0, ushort_t* __restrict__ d1,
    ushort_t* __restrict__ d2, ushort_t* __restrict__ d3)
{
    int i = blockIdx.x * 256 + threadIdx.x;
    if (i < n0) { d0[i] = f2b(s0[i]); return; }
    i -= n0;
    if (i < n1) { d1[i] = f2b(s1[i]); return; }
    i -= n1;
    if (i < n2) { d2[i] = f2b(s2[i]); return; }
    i -= n2;
    if (i < n3) { d3[i] = f2b(s3[i]); }
}

// ---------------------------------------------------------------------------
// Embed (unchanged from round 7).
// ---------------------------------------------------------------------------
__global__ __launch_bounds__(128) void embed_kernel(
    const float* __restrict__ x, const float* __restrict__ prot,
    const float* __restrict__ emb_w, const float* __restrict__ emb_b,
    const float* __restrict__ proj_w, const float* __restrict__ proj_b,
    float* __restrict__ seq, ushort_t* __restrict__ seq_bf)
{
    const int r = blockIdx.x;
    const int t = threadIdx.x;
    __shared__ float xrow[PP];
    __shared__ float sel[PP];

    if (t < PP) xrow[t] = x[r * PP + t];
    __syncthreads();

    float nx = 0.f;
    #pragma unroll
    for (int p = 0; p < PP; ++p) nx += xrow[p] * xrow[p];
    const float xinv = 1.f / fmaxf(sqrtf(nx), 1e-12f);

    const int d = r % DD;
    if (t < KK) {
        const float* pr = prot + (d * KK + t) * PP;
        float pp[PP];
        float np2 = 0.f;
        #pragma unroll
        for (int p = 0; p < PP; ++p) { pp[p] = pr[p]; np2 += pp[p] * pp[p]; }
        const float pinv = 1.f / fmaxf(sqrtf(np2), 1e-12f);
        float dot = 0.f;
        #pragma unroll
        for (int p = 0; p < PP; ++p) dot += xrow[p] * pp[p];
        float sim = dot * xinv * pinv;
        int k = t;
        #pragma unroll
        for (int off = 16; off; off >>= 1) {
            float osim = __shfl_down(sim, off);
            int   ok   = __shfl_down(k, off);
            if (osim > sim || (osim == sim && ok < k)) { sim = osim; k = ok; }
        }
        k = __shfl(k, 0);
        if (t == k) {
            #pragma unroll
            for (int p = 0; p < PP; ++p) sel[p] = pp[p] * pinv;
        }
    }
    __syncthreads();

    float acc = emb_b[t] + proj_b[t];
    #pragma unroll
    for (int p = 0; p < PP; ++p) acc = fmaf(xrow[p], emb_w[t * PP + p], acc);
    #pragma unroll
    for (int p = 0; p < PP; ++p) acc = fmaf(sel[p], proj_w[t * PP + p], acc);

    const int lpos = r % LSEQ;
    const float twoj = (float)((t >> 1) * 2);
    const float div = __expf(twoj * (-9.210340371976184f / 128.0f));
    const float ang = (float)lpos * div;
    const float pe = (t & 1) ? cosf(ang) : sinf(ang);
    const float v = acc + pe;
    seq[(size_t)r * EE + t] = v;
    seq_bf[(size_t)r * EE + t] = f2b(v);
}

// ---------------------------------------------------------------------------
// Direct-activation MFMA GEMM (swapped operands).
// C[M,N] = A[M,K](bf16)@W[N,K]^T + bias. W-tile (64 x K) staged in LDS as the
// MFMA *A*-operand; activation rows read DIRECTLY from global as B-operand
// (frag = 16 rows x 64B = full cachelines, no barrier in k-loop).
// D layout (swapped): row = n (quad*4+r, 4 CONSECUTIVE output cols!),
// col = act row (l16) -> vectorized uint2/float4 stores.
// Block = 128 rows x 64 cols; 4 waves x (2 strips of 16 rows).
// flags: 1 = ELU; 2 = bf16 out; 4 = scale n<128 by 0.25 (Q pre-scale).
// ---------------------------------------------------------------------------
__global__ __launch_bounds__(256) void gemm_direct(
    const ushort_t* __restrict__ A, const ushort_t* __restrict__ W,
    const float* __restrict__ bias, void* __restrict__ Cout,
    int M, int N, int K, int flags)
{
    __shared__ ushort_t Ws[64 * 136];   // kp = K+8 <= 136
    const int t = threadIdx.x;
    const int wave = t >> 6, lane = t & 63;
    const int quad = lane >> 4, l16 = lane & 15;
    const int m0 = blockIdx.y * 128, n0 = blockIdx.x * 64;
    const int kp = K + 8;
    const int ak8 = K >> 3;

    for (int c = t; c < 64 * ak8; c += 256) {
        int row = c / ak8, col = c - row * ak8;
        *(bf16x8*)&Ws[row * kp + col * 8] =
            *(const bf16x8*)&W[(size_t)(n0 + row) * K + col * 8];
    }
    __syncthreads();

    f32x4 acc[2][4];
    #pragma unroll
    for (int s = 0; s < 2; ++s)
        #pragma unroll
        for (int nt = 0; nt < 4; ++nt)
            acc[s][nt] = (f32x4){0.f, 0.f, 0.f, 0.f};

    const ushort_t* a0p = A + (size_t)(m0 + wave * 32 + l16) * K + quad * 8;
    const ushort_t* a1p = a0p + (size_t)16 * K;
    const ushort_t* wp  = &Ws[l16 * kp + quad * 8];

    for (int k0 = 0; k0 < K; k0 += 32) {
        bf16x8 a0 = *(const bf16x8*)(a0p + k0);
        bf16x8 a1 = *(const bf16x8*)(a1p + k0);
        #pragma unroll
        for (int nt = 0; nt < 4; ++nt) {
            bf16x8 wf = *(const bf16x8*)(wp + nt * 16 * kp + k0);
            acc[0][nt] = __builtin_amdgcn_mfma_f32_16x16x32_bf16(wf, a0, acc[0][nt], 0, 0, 0);
            acc[1][nt] = __builtin_amdgcn_mfma_f32_16x16x32_bf16(wf, a1, acc[1][nt], 0, 0, 0);
        }
    }

    #pragma unroll
    for (int s = 0; s < 2; ++s) {
        const int m = m0 + wave * 32 + s * 16 + l16;
        #pragma unroll
        for (int nt = 0; nt < 4; ++nt) {
            const int nb = n0 + nt * 16 + quad * 4;
            float4 b4 = *(const float4*)&bias[nb];
            float v[4];
            #pragma unroll
            for (int r = 0; r < 4; ++r) {
                v[r] = acc[s][nt][r] + ((const float*)&b4)[r];
                if (flags & 1) v[r] = v[r] > 0.f ? v[r] : expm1f(v[r]);
            }
            if ((flags & 4) && nb < EE) {
                #pragma unroll
                for (int r = 0; r < 4; ++r) v[r] *= 0.25f;
            }
            if (flags & 2) {
                uint2 w2;
                w2.x = permpack(v[1], v[0]);
                w2.y = permpack(v[3], v[2]);
                *(uint2*)&((ushort_t*)Cout)[(size_t)m * N + nb] = w2;
            } else {
                float4 f4 = {v[0], v[1], v[2], v[3]};
                *(float4*)&((float*)Cout)[(size_t)m * N + nb] = f4;
            }
        }
    }
}

// ---------------------------------------------------------------------------
// MFMA flash attention v5: + K-frag prefetch (breaks serial chain) and
// XCD-swizzled bh decode (b = bh&31 -> same-b blocks share an XCD L2).
// ---------------------------------------------------------------------------
#define VTS 792
__global__ __launch_bounds__(512) void attention_mfma(
    const ushort_t* __restrict__ qkv, ushort_t* __restrict__ ctx)
{
    __shared__ ushort_t Vt[16 * VTS];

    const int bh = blockIdx.x;
    const int b = bh & 31, h = bh >> 5;     // XCD swizzle: id%8 == b%8
    const int qb = blockIdx.y * 256;
    const int t = threadIdx.x;
    const int wave = t >> 6, lane = t & 63;
    const int quad = lane >> 4, l16 = lane & 15;
    const size_t bbase = (size_t)b * LSEQ * 384;
    const int hoff = h * 16;

    // ---- stage V transposed ----
    for (int idx = t; idx < 1536; idx += 512) {
        int row = idx >> 1, half = idx & 1;
        bf16x8 v = *(const bf16x8*)&qkv[bbase + (size_t)row * 384 + 2 * EE + hoff + half * 8];
        #pragma unroll
        for (int j = 0; j < 8; ++j)
            Vt[(half * 8 + j) * VTS + row] = (ushort_t)v[j];
    }

    // ---- Q fragments ----
    bf16x4 qf[2];
    #pragma unroll
    for (int s = 0; s < 2; ++s) {
        int row = qb + wave * 32 + s * 16 + l16;
        qf[s] = *(const bf16x4*)&qkv[bbase + (size_t)row * 384 + hoff + quad * 4];
    }
    __syncthreads();

    f32x4 oacc[2];
    oacc[0] = (f32x4){0.f, 0.f, 0.f, 0.f};
    oacc[1] = (f32x4){0.f, 0.f, 0.f, 0.f};
    float lsum[2] = {0.f, 0.f};
    const f32x4 zero4 = (f32x4){0.f, 0.f, 0.f, 0.f};

    const ushort_t* kbase = qkv + bbase + EE + hoff + quad * 4;

    bf16x4 kf = *(const bf16x4*)&kbase[(size_t)l16 * 384];   // prefetch ch=0

    for (int ch = 0; ch < LSEQ; ch += 16) {
        bf16x4 kf_next = kf;
        if (ch + 16 < LSEQ)
            kf_next = *(const bf16x4*)&kbase[(size_t)(ch + 16 + l16) * 384];
        bf16x4 vf = *(const bf16x4*)&Vt[l16 * VTS + ch + quad * 4];

        #pragma unroll
        for (int s = 0; s < 2; ++s) {
            f32x4 sv = __builtin_amdgcn_mfma_f32_16x16x16bf16_1k(kf, qf[s], zero4, 0, 0, 0);
            float e0 = __expf(sv[0]), e1 = __expf(sv[1]);
            float e2 = __expf(sv[2]), e3 = __expf(sv[3]);
            lsum[s] += (e0 + e1) + (e2 + e3);
            uint2 pu;
            pu.x = permpack(e1, e0);
            pu.y = permpack(e3, e2);
            bf16x4 pf = __builtin_bit_cast(bf16x4, pu);
            oacc[s] = __builtin_amdgcn_mfma_f32_16x16x16bf16_1k(vf, pf, oacc[s], 0, 0, 0);
        }
        kf = kf_next;
    }

    #pragma unroll
    for (int s = 0; s < 2; ++s) {
        float tot = lsum[s];
        tot += __shfl_xor(tot, 16);
        tot += __shfl_xor(tot, 32);
        const float inv = 1.f / tot;
        const int q = qb + wave * 32 + s * 16 + l16;
        uint2 w2;
        w2.x = permpack(oacc[s][1] * inv, oacc[s][0] * inv);
        w2.y = permpack(oacc[s][3] * inv, oacc[s][2] * inv);
        *(uint2*)&ctx[((size_t)(b * LSEQ + q)) * EE + hoff + quad * 4] = w2;
    }
}

// ---------------------------------------------------------------------------
// Direct-activation GEMM + residual + LayerNorm (N=128).
// seq = LN(seq + A@W^T + bias)*gamma + beta.  Swapped operands: each lane
// owns ONE act row (l16) and 32 of its 128 cols -> LN reduce = in-lane sum
// + shfl_xor(16) + shfl_xor(32). Vectorized float4/uint2 stores.
// Block = 64 rows (4 waves x 16); W (128 x K) in LDS, one barrier.
// ---------------------------------------------------------------------------
__global__ __launch_bounds__(256) void gemm_ln_direct(
    const ushort_t* __restrict__ A, const ushort_t* __restrict__ W,
    const float* __restrict__ bias,
    const float* __restrict__ gamma, const float* __restrict__ beta,
    float* __restrict__ seq, ushort_t* __restrict__ seq_bf, int K)
{
    __shared__ ushort_t Ws[128 * 136];
    const int t = threadIdx.x;
    const int wave = t >> 6, lane = t & 63;
    const int quad = lane >> 4, l16 = lane & 15;
    const int m0 = blockIdx.x * 64;
    const int kp = K + 8;
    const int ak8 = K >> 3;

    for (int c = t; c < 128 * ak8; c += 256) {
        int row = c / ak8, col = c - row * ak8;
        *(bf16x8*)&Ws[row * kp + col * 8] =
            *(const bf16x8*)&W[(size_t)row * K + col * 8];
    }
    __syncthreads();

    f32x4 acc[8];
    #pragma unroll
    for (int nt = 0; nt < 8; ++nt) acc[nt] = (f32x4){0.f, 0.f, 0.f, 0.f};

    const int m = m0 + wave * 16 + l16;
    const ushort_t* ap = A + (size_t)m * K + quad * 8;
    const ushort_t* wp = &Ws[l16 * kp + quad * 8];

    for (int k0 = 0; k0 < K; k0 += 32) {
        bf16x8 a = *(const bf16x8*)(ap + k0);
        #pragma unroll
        for (int nt = 0; nt < 8; ++nt) {
            bf16x8 wf = *(const bf16x8*)(wp + nt * 16 * kp + k0);
            acc[nt] = __builtin_amdgcn_mfma_f32_16x16x32_bf16(wf, a, acc[nt], 0, 0, 0);
        }
    }

    // ---- epilogue: residual + LN over this lane's row m ----
    float v[8][4];
    float s = 0.f;
    #pragma unroll
    for (int nt = 0; nt < 8; ++nt) {
        const int nb = nt * 16 + quad * 4;
        float4 b4 = *(const float4*)&bias[nb];
        float4 r4 = *(const float4*)&seq[(size_t)m * EE + nb];
        #pragma unroll
        for (int r = 0; r < 4; ++r) {
            v[nt][r] = acc[nt][r] + ((const float*)&b4)[r] + ((const float*)&r4)[r];
            s += v[nt][r];
        }
    }
    s += __shfl_xor(s, 16);
    s += __shfl_xor(s, 32);
    const float mean = s * (1.f / 128.f);
    float s2 = 0.f;
    #pragma unroll
    for (int nt = 0; nt < 8; ++nt)
        #pragma unroll
        for (int r = 0; r < 4; ++r) {
            float d = v[nt][r] - mean;
            s2 += d * d;
        }
    s2 += __shfl_xor(s2, 16);
    s2 += __shfl_xor(s2, 32);
    const float rstd = 1.f / sqrtf(s2 * (1.f / 128.f) + 1e-5f);

    #pragma unroll
    for (int nt = 0; nt < 8; ++nt) {
        const int nb = nt * 16 + quad * 4;
        float4 g4 = *(const float4*)&gamma[nb];
        float4 be4 = *(const float4*)&beta[nb];
        float y[4];
        #pragma unroll
        for (int r = 0; r < 4; ++r)
            y[r] = (v[nt][r] - mean) * rstd * ((const float*)&g4)[r] + ((const float*)&be4)[r];
        float4 f4 = {y[0], y[1], y[2], y[3]};
        *(float4*)&seq[(size_t)m * EE + nb] = f4;
        uint2 w2;
        w2.x = permpack(y[1], y[0]);
        w2.y = permpack(y[3], y[2]);
        *(uint2*)&seq_bf[(size_t)m * EE + nb] = w2;
    }
}

// ---------------------------------------------------------------------------
// Fused FFN: seq = LN(seq + elu(seq@W1^T+b1)@W2^T + b2).
// GEMM1: act direct-global, W1 (64x128) LDS; h-tile is WAVE-PRIVATE rows in
// LDS (each wave reads only rows it wrote -> NO barrier between GEMMs).
// GEMM2: h-frags from LDS, W2 (128x64) LDS; epilogue = gemm_ln_direct's.
// Block = 64 rows (4 waves x 16). LDS: W1 17.4K + W2 18.4K + H 9.2K = 45 KB.
// ---------------------------------------------------------------------------
__global__ __launch_bounds__(256) void ffn_fused(
    const ushort_t* __restrict__ seq_bf_in, const ushort_t* __restrict__ W1,
    const float* __restrict__ b1, const ushort_t* __restrict__ W2,
    const float* __restrict__ b2,
    const float* __restrict__ gamma, const float* __restrict__ beta,
    float* __restrict__ seq, ushort_t* __restrict__ seq_bf)
{
    __shared__ ushort_t W1s[64 * 136];   // kp1 = 136 (K=128)
    __shared__ ushort_t W2s[128 * 72];   // kp2 = 72  (K=64)
    __shared__ ushort_t Hs[64 * 72];     // h rows, wave-partitioned
    const int t = threadIdx.x;
    const int wave = t >> 6, lane = t & 63;
    const int quad = lane >> 4, l16 = lane & 15;
    const int m0 = blockIdx.x * 64;

    for (int c = t; c < 64 * 16; c += 256) {
        int row = c >> 4, col = c & 15;
        *(bf16x8*)&W1s[row * 136 + col * 8] =
            *(const bf16x8*)&W1[(size_t)row * 128 + col * 8];
    }
    for (int c = t; c < 128 * 8; c += 256) {
        int row = c >> 3, col = c & 7;
        *(bf16x8*)&W2s[row * 72 + col * 8] =
            *(const bf16x8*)&W2[(size_t)row * 64 + col * 8];
    }
    __syncthreads();

    // ---- GEMM1: h = elu(seq @ W1^T + b1), rows m = m0 + wave*16 + l16 ----
    const int lrow = wave * 16 + l16;     // local row, this lane's row
    const int m = m0 + lrow;
    f32x4 acc1[4];
    #pragma unroll
    for (int nt = 0; nt < 4; ++nt) acc1[nt] = (f32x4){0.f, 0.f, 0.f, 0.f};

    const ushort_t* ap = seq_bf_in + (size_t)m * EE + quad * 8;
    const ushort_t* w1p = &W1s[l16 * 136 + quad * 8];
    for (int k0 = 0; k0 < 128; k0 += 32) {
        bf16x8 a = *(const bf16x8*)(ap + k0);
        #pragma unroll
        for (int nt = 0; nt < 4; ++nt) {
            bf16x8 wf = *(const bf16x8*)(w1p + nt * 16 * 136 + k0);
            acc1[nt] = __builtin_amdgcn_mfma_f32_16x16x32_bf16(wf, a, acc1[nt], 0, 0, 0);
        }
    }
    #pragma unroll
    for (int nt = 0; nt < 4; ++nt) {
        const int ib = nt * 16 + quad * 4;
        float4 b4 = *(const float4*)&b1[ib];
        float hv[4];
        #pragma unroll
        for (int r = 0; r < 4; ++r) {
            float u = acc1[nt][r] + ((const float*)&b4)[r];
            hv[r] = u > 0.f ? u : expm1f(u);
        }
        uint2 w2;
        w2.x = permpack(hv[1], hv[0]);
        w2.y = permpack(hv[3], hv[2]);
        *(uint2*)&Hs[lrow * 72 + ib] = w2;   // wave-private rows: no barrier
    }

    // ---- GEMM2: ffn_out = h @ W2^T + b2 (reads only this lane's row) ----
    f32x4 acc2[8];
    #pragma unroll
    for (int nt = 0; nt < 8; ++nt) acc2[nt] = (f32x4){0.f, 0.f, 0.f, 0.f};
    const ushort_t* hp = &Hs[lrow * 72 + quad * 8];
    const ushort_t* w2p = &W2s[l16 * 72 + quad * 8];
    #pragma unroll
    for (int k0 = 0; k0 < 64; k0 += 32) {
        bf16x8 hf = *(const bf16x8*)(hp + k0);
        #pragma unroll
        for (int nt = 0; nt < 8; ++nt) {
            bf16x8 wf = *(const bf16x8*)(w2p + nt * 16 * 72 + k0);
            acc2[nt] = __builtin_amdgcn_mfma_f32_16x16x32_bf16(wf, hf, acc2[nt], 0, 0, 0);
        }
    }

    // ---- epilogue: residual + LN over row m ----
    float v[8][4];
    float s = 0.f;
    #pragma unroll
    for (int nt = 0; nt < 8; ++nt) {
        const int nb = nt * 16 + quad * 4;
        float4 b4 = *(const float4*)&b2[nb];
        float4 r4 = *(const float4*)&seq[(size_t)m * EE + nb];
        #pragma unroll
        for (int r = 0; r < 4; ++r) {
            v[nt][r] = acc2[nt][r] + ((const float*)&b4)[r] + ((const float*)&r4)[r];
            s += v[nt][r];
        }
    }
    s += __shfl_xor(s, 16);
    s += __shfl_xor(s, 32);
    const float mean = s * (1.f / 128.f);
    float s2 = 0.f;
    #pragma unroll
    for (int nt = 0; nt < 8; ++nt)
        #pragma unroll
        for (int r = 0; r < 4; ++r) {
            float d = v[nt][r] - mean;
            s2 += d * d;
        }
    s2 += __shfl_xor(s2, 16);
    s2 += __shfl_xor(s2, 32);
    const float rstd = 1.f / sqrtf(s2 * (1.f / 128.f) + 1e-5f);

    #pragma unroll
    for (int nt = 0; nt < 8; ++nt) {
        const int nb = nt * 16 + quad * 4;
        float4 g4 = *(const float4*)&gamma[nb];
        float4 be4 = *(const float4*)&beta[nb];
        float y[4];
        #pragma unroll
        for (int r = 0; r < 4; ++r)
            y[r] = (v[nt][r] - mean) * rstd * ((const float*)&g4)[r] + ((const float*)&be4)[r];
        float4 f4 = {y[0], y[1], y[2], y[3]};
        *(float4*)&seq[(size_t)m * EE + nb] = f4;
        uint2 w2;
        w2.x = permpack(y[1], y[0]);
        w2.y = permpack(y[3], y[2]);
        *(uint2*)&seq_bf[(size_t)m * EE + nb] = w2;
    }
}

// ---------------------------------------------------------------------------
// Final projection, split-K MFMA (unchanged from round 7).
// ---------------------------------------------------------------------------
#define PKC 192
#define PNBLK (KOUT / PKC)   // 512
__global__ __launch_bounds__(256) void out_gemm3(
    const ushort_t* __restrict__ seqbf, const float* __restrict__ out_w,
    float* __restrict__ part)
{
    const int t = threadIdx.x;
    const int wave = t >> 6, lane = t & 63;
    const int quad = lane >> 4, l16 = lane & 15;
    const size_t k0 = (size_t)blockIdx.x * PKC;
    const int n0 = wave * 32;

    f32x4 acc[2][2];
    #pragma unroll
    for (int mt = 0; mt < 2; ++mt)
        #pragma unroll
        for (int nt = 0; nt < 2; ++nt)
            acc[mt][nt] = (f32x4){0.f, 0.f, 0.f, 0.f};

    const ushort_t* a0p = seqbf + (size_t)l16 * KOUT + k0 + quad * 8;
    const ushort_t* a1p = a0p + (size_t)16 * KOUT;
    const float* w0p = out_w + (size_t)(n0 + l16) * KOUT + k0 + quad * 8;
    const float* w1p = w0p + (size_t)16 * KOUT;

    #pragma unroll
    for (int ks = 0; ks < PKC; ks += 32) {
        bf16x8 a0 = *(const bf16x8*)(a0p + ks);
        bf16x8 a1 = *(const bf16x8*)(a1p + ks);
        float4 wa0 = *(const float4*)(w0p + ks);
        float4 wa1 = *(const float4*)(w0p + ks + 4);
        float4 wb0 = *(const float4*)(w1p + ks);
        float4 wb1 = *(const float4*)(w1p + ks + 4);
        u32x4 b0, b1;
        b0[0] = permpack(wa0.y, wa0.x); b0[1] = permpack(wa0.w, wa0.z);
        b0[2] = permpack(wa1.y, wa1.x); b0[3] = permpack(wa1.w, wa1.z);
        b1[0] = permpack(wb0.y, wb0.x); b1[1] = permpack(wb0.w, wb0.z);
        b1[2] = permpack(wb1.y, wb1.x); b1[3] = permpack(wb1.w, wb1.z);
        bf16x8 bf0 = __builtin_bit_cast(bf16x8, b0);
        bf16x8 bf1 = __builtin_bit_cast(bf16x8, b1);
        acc[0][0] = __builtin_amdgcn_mfma_f32_16x16x32_bf16(a0, bf0, acc[0][0], 0, 0, 0);
        acc[1][0] = __builtin_amdgcn_mfma_f32_16x16x32_bf16(a1, bf0, acc[1][0], 0, 0, 0);
        acc[0][1] = __builtin_amdgcn_mfma_f32_16x16x32_bf16(a0, bf1, acc[0][1], 0, 0, 0);
        acc[1][1] = __builtin_amdgcn_mfma_f32_16x16x32_bf16(a1, bf1, acc[1][1], 0, 0, 0);
    }

    float* pb = part + (size_t)blockIdx.x * (32 * 128);
    #pragma unroll
    for (int mt = 0; mt < 2; ++mt)
        #pragma unroll
        for (int nt = 0; nt < 2; ++nt)
            #pragma unroll
            for (int r = 0; r < 4; ++r)
                pb[(mt * 16 + quad * 4 + r) * 128 + n0 + nt * 16 + l16] = acc[mt][nt][r];
}

__global__ __launch_bounds__(256) void out_reduce(
    const float* __restrict__ part, const float* __restrict__ out_b,
    float* __restrict__ out)
{
    const int i = blockIdx.x * 256 + threadIdx.x;
    const float* p = part + i;
    float s0 = 0.f, s1 = 0.f, s2 = 0.f, s3 = 0.f;
    for (int blk = 0; blk < PNBLK; blk += 4) {
        s0 += p[(size_t)blk * 4096];
        s1 += p[(size_t)(blk + 1) * 4096];
        s2 += p[(size_t)(blk + 2) * 4096];
        s3 += p[(size_t)(blk + 3) * 4096];
    }
    out[i] = out_b[i & (OUTN - 1)] + ((s0 + s1) + (s2 + s3));
}

// ---------------------------------------------------------------------------
extern "C" void kernel_launch(void* const* d_in, const int* in_sizes, int n_in,
                              void* d_out, int out_size, void* d_ws, size_t ws_size,
                              hipStream_t stream)
{
    const float* x          = (const float*)d_in[0];
    const float* prototypes = (const float*)d_in[1];
    const float* emb_w      = (const float*)d_in[2];
    const float* emb_b      = (const float*)d_in[3];
    const float* proj_w     = (const float*)d_in[4];
    const float* proj_b     = (const float*)d_in[5];
    const float* in_proj_w  = (const float*)d_in[6];
    const float* in_proj_b  = (const float*)d_in[7];
    const float* out_proj_w = (const float*)d_in[8];
    const float* out_proj_b = (const float*)d_in[9];
    const float* ln1_s      = (const float*)d_in[10];
    const float* ln1_b      = (const float*)d_in[11];
    const float* ffn_w1     = (const float*)d_in[12];
    const float* ffn_b1     = (const float*)d_in[13];
    const float* ffn_w2     = (const float*)d_in[14];
    const float* ffn_b2     = (const float*)d_in[15];
    const float* ln2_s      = (const float*)d_in[16];
    const float* ln2_b      = (const float*)d_in[17];
    const float* out_w      = (const float*)d_in[18];
    const float* out_b      = (const float*)d_in[19];
    float* out = (float*)d_out;
    char* base = (char*)d_ws;

    float*    seq    = (float*)base;                        // 12,582,912
    float*    tmp    = (float*)(base + 12582912);           // 12,582,912 (= part)
    ushort_t* seq_bf = (ushort_t*)(base + 25165824);        //  6,291,456
    ushort_t* qkv_bf = (ushort_t*)(base + 31457280);        // 18,874,368
    ushort_t* ctx_bf = (ushort_t*)(base + 50331648);        //  6,291,456
    ushort_t* w_bf   = (ushort_t*)(base + 56623104);        //    327,680
    float*    part   = tmp;
    (void)ws_size;

    ushort_t* w_in  = w_bf;            // [2][384][128]
    ushort_t* w_out = w_bf + 98304;    // [2][128][128]
    ushort_t* w_f1  = w_bf + 131072;   // [2][64][128]
    ushort_t* w_f2  = w_bf + 147456;   // [2][128][64]

    cast_all_kernel<<<(163840 + 255) / 256, 256, 0, stream>>>(
        in_proj_w, 98304, out_proj_w, 32768, ffn_w1, 16384, ffn_w2, 16384,
        w_in, w_out, w_f1, w_f2);

    embed_kernel<<<ROWS, 128, 0, stream>>>(x, prototypes, emb_w, emb_b,
                                           proj_w, proj_b, seq, seq_bf);

    for (int l = 0; l < 2; ++l) {
        // qkv = seq @ Wqkv^T + b -> bf16 [24576, 384], Q cols pre-scaled 0.25
        gemm_direct<<<dim3(6, 192), 256, 0, stream>>>(
            seq_bf, w_in + (size_t)l * 49152, in_proj_b + l * 384,
            qkv_bf, ROWS, 384, 128, 2 | 4);
        attention_mfma<<<dim3(BB * HH, 3), 512, 0, stream>>>(qkv_bf, ctx_bf);
        // seq = LN(seq + ctx @ Wout^T + b)
        gemm_ln_direct<<<ROWS / 64, 256, 0, stream>>>(
            ctx_bf, w_out + (size_t)l * 16384, out_proj_b + l * 128,
            ln1_s + l * EE, ln1_b + l * EE, seq, seq_bf, 128);
        // seq = LN(seq + elu(seq@W1^T+b1)@W2^T + b2)  (fully fused FFN)
        ffn_fused<<<ROWS / 64, 256, 0, stream>>>(
            seq_bf, w_f1 + (size_t)l * 8192, ffn_b1 + l * II,
            w_f2 + (size_t)l * 8192, ffn_b2 + l * EE,
            ln2_s + l * EE, ln2_b + l * EE, seq, seq_bf);
    }

    out_gemm3<<<PNBLK, 256, 0, stream>>>(seq_bf, out_w, part);
    out_reduce<<<BB * OUTN / 256, 256, 0, stream>>>(part, out_b, out);
}